// Round 6
// baseline (351.219 us; speedup 1.0000x reference)
//
#include <hip/hip_runtime.h>
#include <math.h>

#define HH 56
#define WW 56
#define CC 256
#define TT 8
#define HW 3136

// ---------------- K1: attn partial conv2d, row-per-wave, shuffle taps -----
// grid = bt(32) x rowband(14 of 4 rows) x csplit(4 of 64 ch) = 1792 blocks.
// Wave owns one output row; lane = column. Per channel: 3 vertical loads
// (row-1,row,row+1 at own column), horizontal taps via __shfl_up/down.
// unroll 16 -> 48 loads in flight per wave: hides ~900cyc HBM/L3 latency
// (unroll 4 left each wave ~90% stalled; VALUBusy was 31%).
__global__ __launch_bounds__(256)
void k1_attn(const float* __restrict__ x, const float* __restrict__ aw,
             float* __restrict__ attn_raw) {
    const int blk  = blockIdx.x;
    const int cs   = blk & 3;
    const int ht   = (blk >> 2) % 14;
    const int bt   = blk / 56;
    const int wave = threadIdx.x >> 6;
    const int lane = threadIdx.x & 63;
    const int row  = ht * 4 + wave;
    const int col  = lane;
    const bool live = col < WW;
    const bool okm = row > 0, okp = row < HH - 1;
    const int base = row * WW + col;
    const int offm = okm ? base - WW : base;   // clamped (safe) address
    const int offp = okp ? base + WW : base;
    const float* xb = x + ((size_t)bt * CC + cs * 64) * HW;

    float a0 = 0.f, a1 = 0.f, a2 = 0.f, a3 = 0.f;
    #pragma unroll 16
    for (int cl = 0; cl < 64; ++cl) {
        const float* xp = xb + (size_t)cl * HW;
        float vm = (live && okm) ? xp[offm] : 0.f;
        float vc = live ? xp[base] : 0.f;
        float vp = (live && okp) ? xp[offp] : 0.f;
        // horizontal neighbors via cross-lane shuffle (lanes>=56 hold 0)
        float vml = __shfl_up(vm, 1), vcl = __shfl_up(vc, 1), vpl = __shfl_up(vp, 1);
        if (lane == 0) { vml = 0.f; vcl = 0.f; vpl = 0.f; }
        float vmr = __shfl_down(vm, 1), vcr = __shfl_down(vc, 1), vpr = __shfl_down(vp, 1);

        const int c = cs * 64 + cl;
        const float* w0 = aw + ((size_t)0 * CC + c) * 9;   // uniform -> s_load
        const float* w1 = aw + ((size_t)1 * CC + c) * 9;
        const float* w2 = aw + ((size_t)2 * CC + c) * 9;
        const float* w3 = aw + ((size_t)3 * CC + c) * 9;

        a0 = fmaf(w0[0], vml, a0); a0 = fmaf(w0[1], vm, a0); a0 = fmaf(w0[2], vmr, a0);
        a0 = fmaf(w0[3], vcl, a0); a0 = fmaf(w0[4], vc, a0); a0 = fmaf(w0[5], vcr, a0);
        a0 = fmaf(w0[6], vpl, a0); a0 = fmaf(w0[7], vp, a0); a0 = fmaf(w0[8], vpr, a0);

        a1 = fmaf(w1[0], vml, a1); a1 = fmaf(w1[1], vm, a1); a1 = fmaf(w1[2], vmr, a1);
        a1 = fmaf(w1[3], vcl, a1); a1 = fmaf(w1[4], vc, a1); a1 = fmaf(w1[5], vcr, a1);
        a1 = fmaf(w1[6], vpl, a1); a1 = fmaf(w1[7], vp, a1); a1 = fmaf(w1[8], vpr, a1);

        a2 = fmaf(w2[0], vml, a2); a2 = fmaf(w2[1], vm, a2); a2 = fmaf(w2[2], vmr, a2);
        a2 = fmaf(w2[3], vcl, a2); a2 = fmaf(w2[4], vc, a2); a2 = fmaf(w2[5], vcr, a2);
        a2 = fmaf(w2[6], vpl, a2); a2 = fmaf(w2[7], vp, a2); a2 = fmaf(w2[8], vpr, a2);

        a3 = fmaf(w3[0], vml, a3); a3 = fmaf(w3[1], vm, a3); a3 = fmaf(w3[2], vmr, a3);
        a3 = fmaf(w3[3], vcl, a3); a3 = fmaf(w3[4], vc, a3); a3 = fmaf(w3[5], vcr, a3);
        a3 = fmaf(w3[6], vpl, a3); a3 = fmaf(w3[7], vp, a3); a3 = fmaf(w3[8], vpr, a3);
    }
    if (live) {
        atomicAdd(&attn_raw[((size_t)bt * 4 + 0) * HW + base], a0);
        atomicAdd(&attn_raw[((size_t)bt * 4 + 1) * HW + base], a1);
        atomicAdd(&attn_raw[((size_t)bt * 4 + 2) * HW + base], a2);
        atomicAdd(&attn_raw[((size_t)bt * 4 + 3) * HW + base], a3);
    }
}

// ---------------- K1b: attn = sigmoid(relu(raw + bias)) -------------------
__global__ void k1b_act(const float* __restrict__ raw, const float* __restrict__ ab,
                        float* __restrict__ attn) {
    int i = blockIdx.x * 256 + threadIdx.x;
    if (i >= 32 * 4 * HW) return;
    int o = (i / HW) & 3;
    float z = fmaxf(raw[i] + ab[o], 0.f);
    attn[i] = 1.f / (1.f + expf(-z));
}

// ---------------- K2: per-channel BN partial sums of xh = x*attn ----------
__global__ __launch_bounds__(256)
void k2_stats(const float* __restrict__ x, const float* __restrict__ attn,
              float* __restrict__ bn_sum, float* __restrict__ bn_sumsq) {
    const int c  = blockIdx.x & 255;
    const int bt = blockIdx.x >> 8;
    const int head = c >> 6;
    const float4* xp = (const float4*)(x + ((size_t)bt * CC + c) * HW);
    const float4* ap = (const float4*)(attn + ((size_t)bt * 4 + head) * HW);
    float s = 0.f, s2 = 0.f;
    for (int i = threadIdx.x; i < HW / 4; i += 256) {
        float4 xv = xp[i], av = ap[i];
        float v0 = xv.x * av.x, v1 = xv.y * av.y, v2 = xv.z * av.z, v3 = xv.w * av.w;
        s  += v0 + v1 + v2 + v3;
        s2 += v0 * v0 + v1 * v1 + v2 * v2 + v3 * v3;
    }
    #pragma unroll
    for (int off = 32; off > 0; off >>= 1) {
        s  += __shfl_down(s, off);
        s2 += __shfl_down(s2, off);
    }
    __shared__ float red[8];
    const int wave = threadIdx.x >> 6;
    if ((threadIdx.x & 63) == 0) { red[wave * 2] = s; red[wave * 2 + 1] = s2; }
    __syncthreads();
    if (threadIdx.x == 0) {
        atomicAdd(&bn_sum[c],   red[0] + red[2] + red[4] + red[6]);
        atomicAdd(&bn_sumsq[c], red[1] + red[3] + red[5] + red[7]);
    }
}

// ---------------- K3: finalize BN -> per-channel scale/shift --------------
__global__ void k3_final(const float* __restrict__ bn_sum, const float* __restrict__ bn_sumsq,
                         const float* __restrict__ gamma, const float* __restrict__ beta,
                         float* __restrict__ scale, float* __restrict__ shift) {
    int c = threadIdx.x;
    const float invN = 1.f / 100352.f;            // B*T*H*W
    float mean = bn_sum[c] * invN;
    float var  = bn_sumsq[c] * invN - mean * mean;
    float sc   = gamma[c] * rsqrtf(var + 1e-5f);
    scale[c] = sc;
    shift[c] = fmaf(-mean, sc, beta[c]);
}

// ---------------- K4: grouped dilated conv3d, LDS-staged, double-buffered -
__global__ __launch_bounds__(256)
void k4_gate(const float* __restrict__ x, const float* __restrict__ attn,
             const float* __restrict__ scale, const float* __restrict__ shift,
             const float* __restrict__ gw0, const float* __restrict__ gw1,
             float* __restrict__ gate_raw) {
    const int blk   = blockIdx.x;
    const int chunk = blk & 31;             // 32 chunks x 8 channels
    const int ht    = (blk >> 5) % 14;
    const int b     = blk / (32 * 14);
    const int h0    = ht * 4;
    const int g     = chunk >> 4;           // group: ch 0..127 -> 0, else 1
    const int head  = chunk >> 3;           // 8-ch chunk sits inside one head
    __shared__ float tile[2][TT * 6 * 58];  // 22272 B
    float* tf = &tile[0][0];
    const int tid = threadIdx.x;

    // per-thread staging descriptors (channel-independent), elems 2784
    int   soff[11];
    int   goff[11];
    float av[11];
    bool  vld[11];
    #pragma unroll
    for (int k = 0; k < 11; ++k) {
        int idx = tid + k * 256;
        bool in = idx < TT * 6 * 58;
        int t   = idx / 348;
        int rem = idx - t * 348;
        int r   = rem / 58;
        int col = rem - r * 58;
        int gh = h0 + r - 1, gw = col - 1;
        bool v = in && (unsigned)gh < HH && (unsigned)gw < WW;
        vld[k]  = v;
        soff[k] = idx;
        goff[k] = ((b * 8 + t) * CC) * HW + gh * WW + gw;
        av[k]   = v ? attn[((size_t)(b * 8 + t) * 4 + head) * HW + gh * WW + gw] : 0.f;
        if (in && !v) { tf[idx] = 0.f; tf[2784 + idx] = 0.f; }
    }

    {
        const int c0 = chunk * 8;
        const float sc = scale[c0], sh = shift[c0];
        #pragma unroll
        for (int k = 0; k < 11; ++k)
            if (vld[k]) {
                float xv = x[(size_t)goff[k] + (size_t)c0 * HW];
                tf[soff[k]] = fmaxf(fmaf(xv * av[k], sc, sh), 0.f);
            }
    }
    __syncthreads();

    const int wc = tid % WW;
    const int hr = tid / WW;
    const bool active = tid < 4 * WW;
    float acc[2][8];
    #pragma unroll
    for (int d = 0; d < 2; ++d)
        #pragma unroll
        for (int t = 0; t < 8; ++t) acc[d][t] = 0.f;

    for (int cl = 0; cl < 8; ++cl) {
        const int c = chunk * 8 + cl;
        float xv[11];
        if (cl < 7) {
            #pragma unroll
            for (int k = 0; k < 11; ++k)
                xv[k] = vld[k] ? x[(size_t)goff[k] + (size_t)(c + 1) * HW] : 0.f;
        }
        if (active) {
            const float* buf = tf + (cl & 1) * 2784;
            const int ci = c & 127;
            const float* wp0 = gw0 + ((size_t)g * 128 + ci) * 27;
            const float* wp1 = gw1 + ((size_t)g * 128 + ci) * 27;
            #pragma unroll
            for (int t = 0; t < 8; ++t) {
                float v[9];
                #pragma unroll
                for (int ki = 0; ki < 3; ++ki)
                    #pragma unroll
                    for (int kj = 0; kj < 3; ++kj)
                        v[ki * 3 + kj] = buf[t * 348 + (hr + ki) * 58 + wc + kj];
                #pragma unroll
                for (int kd = 0; kd < 3; ++kd) {
                    {
                        const int to = t + 1 - kd;
                        if (to >= 0 && to < 8) {
                            float s = 0.f;
                            #pragma unroll
                            for (int k = 0; k < 9; ++k) s = fmaf(wp0[kd * 9 + k], v[k], s);
                            acc[0][to] += s;
                        }
                    }
                    {
                        const int to = t + 2 - 2 * kd;
                        if (to >= 0 && to < 8) {
                            float s = 0.f;
                            #pragma unroll
                            for (int k = 0; k < 9; ++k) s = fmaf(wp1[kd * 9 + k], v[k], s);
                            acc[1][to] += s;
                        }
                    }
                }
            }
        }
        if (cl < 7) {
            const float scn = scale[c + 1], shn = shift[c + 1];
            float* bufn = tf + ((cl + 1) & 1) * 2784;
            #pragma unroll
            for (int k = 0; k < 11; ++k)
                if (vld[k])
                    bufn[soff[k]] = fmaxf(fmaf(xv[k] * av[k], scn, shn), 0.f);
        }
        __syncthreads();
    }

    if (active) {
        const int hw = (h0 + hr) * WW + wc;
        #pragma unroll
        for (int d = 0; d < 2; ++d)
            #pragma unroll
            for (int t = 0; t < 8; ++t)
                atomicAdd(&gate_raw[(((size_t)(d * 4 + b) * 2 + g) * 8 + t) * HW + hw],
                          acc[d][t]);
    }
}

// ---------------- K4b: gate = tanh(raw + bias) ----------------------------
__global__ void k4b_tanh(const float* __restrict__ raw, const float* __restrict__ gb0,
                         const float* __restrict__ gb1, float* __restrict__ gt) {
    int i = blockIdx.x * 256 + threadIdx.x;
    if (i >= 401408) return;
    int d   = i / 200704;
    int rem = i - d * 200704;
    int g   = (rem / 25088) & 1;
    float bias = (d == 0) ? gb0[g] : gb1[g];
    gt[i] = tanhf(raw[i] + bias);
}

// ---------------- K5: fuse + shuffle + alpha-combine ----------------------
__global__ __launch_bounds__(256)
void k5_fuse(const float* __restrict__ x, const float* __restrict__ attn,
             const float* __restrict__ scale, const float* __restrict__ shift,
             const float* __restrict__ gt, const float* __restrict__ alpha,
             float* __restrict__ out) {
    const int blk  = blockIdx.x;
    const int tile = blk % 13;
    const int c    = (blk / 13) & 255;
    const int b    = blk / (13 * 256);
    const int hw   = tile * 256 + threadIdx.x;
    if (hw >= HW) return;
    const int clo  = c & 127;
    const int cs   = (c & 128) | ((clo & 1) << 6) | (clo >> 1);  // inverse shuffle
    const int g    = c >> 7;
    const int head = cs >> 6;
    const float sc = scale[cs], sh = shift[cs];
    float xr[8], G0[8], G1[8];
    #pragma unroll
    for (int t = 0; t < 8; ++t) {
        const int bti = b * 8 + t;
        float xv = x[((size_t)bti * CC + cs) * HW + hw];
        float av = attn[((size_t)bti * 4 + head) * HW + hw];
        xr[t] = fmaxf(fmaf(xv * av, sc, sh), 0.f);
        G0[t] = gt[(((size_t)(0 * 4 + b) * 2 + g) * 8 + t) * HW + hw];
        G1[t] = gt[(((size_t)(1 * 4 + b) * 2 + g) * 8 + t) * HW + hw];
    }
    const float a0 = alpha[0], a1 = alpha[1];
    #pragma unroll
    for (int t = 0; t < 8; ++t) {
        float v0, v1;
        if (g == 0) {
            v0 = xr[t] * (1.f - G0[t]) + (t + 1 < 8 ? G0[t + 1] * xr[t + 1] : 0.f);
            v1 = xr[t] * (1.f - G1[t]) + (t + 2 < 8 ? G1[t + 2] * xr[t + 2] : 0.f);
        } else {
            v0 = xr[t] * (1.f - G0[t]) + (t - 1 >= 0 ? G0[t - 1] * xr[t - 1] : 0.f);
            v1 = xr[t] * (1.f - G1[t]) + (t - 2 >= 0 ? G1[t - 2] * xr[t - 2] : 0.f);
        }
        out[((size_t)(b * 8 + t) * CC + c) * HW + hw] = fmaf(a0, v0, a1 * v1);
    }
}

extern "C" void kernel_launch(void* const* d_in, const int* in_sizes, int n_in,
                              void* d_out, int out_size, void* d_ws, size_t ws_size,
                              hipStream_t stream) {
    const float* x     = (const float*)d_in[0];
    const float* aw    = (const float*)d_in[1];
    const float* ab    = (const float*)d_in[2];
    const float* gamma = (const float*)d_in[3];
    const float* beta  = (const float*)d_in[4];
    const float* gw0   = (const float*)d_in[5];
    const float* gb0   = (const float*)d_in[6];
    const float* gw1   = (const float*)d_in[7];
    const float* gb1   = (const float*)d_in[8];
    const float* alpha = (const float*)d_in[9];
    float* out = (float*)d_out;
    float* ws  = (float*)d_ws;

    // ws layout (floats):
    //   [gate_raw 401408 | attn_raw/gate_t 401408 | bn_sum 256 | bn_sumsq 256 |
    //    attn 401408 | scale 256 | shift 256]
    float* gate_raw = ws;
    float* attn_raw = ws + 401408;
    float* gate_t   = attn_raw;             // alias (timeline-disjoint)
    float* bn_sum   = ws + 802816;
    float* bn_sumsq = ws + 803072;
    float* attn     = ws + 803328;
    float* scale    = ws + 1204736;
    float* shift    = ws + 1204992;

    // zero all atomic-accumulated regions in one memset (contiguous prefix)
    hipMemsetAsync(ws, 0, (size_t)(401408 + 401408 + 512) * sizeof(float), stream);

    k1_attn <<<dim3(1792),  dim3(256), 0, stream>>>(x, aw, attn_raw);
    k1b_act <<<dim3(1568),  dim3(256), 0, stream>>>(attn_raw, ab, attn);
    k2_stats<<<dim3(8192),  dim3(256), 0, stream>>>(x, attn, bn_sum, bn_sumsq);
    k3_final<<<dim3(1),     dim3(256), 0, stream>>>(bn_sum, bn_sumsq, gamma, beta, scale, shift);
    k4_gate <<<dim3(1792),  dim3(256), 0, stream>>>(x, attn, scale, shift, gw0, gw1, gate_raw);
    k4b_tanh<<<dim3(1568),  dim3(256), 0, stream>>>(gate_raw, gb0, gb1, gate_t);
    k5_fuse <<<dim3(13312), dim3(256), 0, stream>>>(x, attn, scale, shift, gate_t, alpha, out);
}

// Round 7
// 236.735 us; speedup vs baseline: 1.4836x; 1.4836x over previous
//
#include <hip/hip_runtime.h>
#include <math.h>

#define HH 56
#define WW 56
#define CC 256
#define TT 8
#define HW 3136

// ---------------- K1: attn partial conv2d, float4-quad per thread ---------
// grid = bt(32) x csplit(8 of 32ch) x qtile(7 of 112 quads) = 1792 blocks,
// block = 128 (112 active). Thread owns 4 output cols (one float4 quad).
// Per channel: 3x(float4 + 2 halo scalars) = 9 loads feed 144 FMAs (16:1).
// No LDS, no barriers, no shuffles. Weights wave-uniform -> scalar loads.
__global__ __launch_bounds__(128)
void k1_attn(const float* __restrict__ x, const float* __restrict__ aw,
             float* __restrict__ attn_raw) {
    const int blk   = blockIdx.x;
    const int cs    = blk & 7;
    const int qtile = (blk >> 3) % 7;
    const int bt    = blk / 56;
    const int tid   = threadIdx.x;
    if (tid >= 112) return;
    const int qi   = qtile * 112 + tid;      // 0..783
    const int row  = qi / 14;
    const int qc   = qi - row * 14;
    const int col0 = qc * 4;
    const bool okm = row > 0, okp = row < HH - 1;
    const bool okl = qc > 0,  okr = qc < 13;
    const int base  = row * WW + col0;
    const int basem = okm ? base - WW : base;    // clamped (safe) addresses
    const int basep = okp ? base + WW : base;
    const float* xb = x + ((size_t)bt * CC + cs * 32) * HW;
    const float4 f4z = make_float4(0.f, 0.f, 0.f, 0.f);

    float acc[4][4];
    #pragma unroll
    for (int h = 0; h < 4; ++h)
        #pragma unroll
        for (int j = 0; j < 4; ++j) acc[h][j] = 0.f;

    #pragma unroll 2
    for (int cl = 0; cl < 32; ++cl) {
        const int c = cs * 32 + cl;
        const float* xp = xb + (size_t)cl * HW;
        float4 Cm = *(const float4*)(xp + basem);
        float  Lm = okl ? xp[basem - 1] : 0.f;
        float  Rm = okr ? xp[basem + 4] : 0.f;
        float4 Cc = *(const float4*)(xp + base);
        float  Lc = okl ? xp[base - 1] : 0.f;
        float  Rc = okr ? xp[base + 4] : 0.f;
        float4 Cp = *(const float4*)(xp + basep);
        float  Lp = okl ? xp[basep - 1] : 0.f;
        float  Rp = okr ? xp[basep + 4] : 0.f;
        if (!okm) { Cm = f4z; Lm = 0.f; Rm = 0.f; }
        if (!okp) { Cp = f4z; Lp = 0.f; Rp = 0.f; }

        #pragma unroll
        for (int h = 0; h < 4; ++h) {
            const float* w = aw + ((size_t)h * CC + c) * 9;
            const float w0 = w[0], w1 = w[1], w2 = w[2];
            const float w3 = w[3], w4 = w[4], w5 = w[5];
            const float w6 = w[6], w7 = w[7], w8 = w[8];
            acc[h][0] = fmaf(w0, Lm,   fmaf(w1, Cm.x, fmaf(w2, Cm.y,
                        fmaf(w3, Lc,   fmaf(w4, Cc.x, fmaf(w5, Cc.y,
                        fmaf(w6, Lp,   fmaf(w7, Cp.x, fmaf(w8, Cp.y, acc[h][0])))))))));
            acc[h][1] = fmaf(w0, Cm.x, fmaf(w1, Cm.y, fmaf(w2, Cm.z,
                        fmaf(w3, Cc.x, fmaf(w4, Cc.y, fmaf(w5, Cc.z,
                        fmaf(w6, Cp.x, fmaf(w7, Cp.y, fmaf(w8, Cp.z, acc[h][1])))))))));
            acc[h][2] = fmaf(w0, Cm.y, fmaf(w1, Cm.z, fmaf(w2, Cm.w,
                        fmaf(w3, Cc.y, fmaf(w4, Cc.z, fmaf(w5, Cc.w,
                        fmaf(w6, Cp.y, fmaf(w7, Cp.z, fmaf(w8, Cp.w, acc[h][2])))))))));
            acc[h][3] = fmaf(w0, Cm.z, fmaf(w1, Cm.w, fmaf(w2, Rm,
                        fmaf(w3, Cc.z, fmaf(w4, Cc.w, fmaf(w5, Rc,
                        fmaf(w6, Cp.z, fmaf(w7, Cp.w, fmaf(w8, Rp, acc[h][3])))))))));
        }
    }
    #pragma unroll
    for (int h = 0; h < 4; ++h)
        #pragma unroll
        for (int j = 0; j < 4; ++j)
            atomicAdd(&attn_raw[((size_t)bt * 4 + h) * HW + base + j], acc[h][j]);
}

// ---------------- K1b: attn = sigmoid(relu(raw + bias)) -------------------
__global__ void k1b_act(const float* __restrict__ raw, const float* __restrict__ ab,
                        float* __restrict__ attn) {
    int i = blockIdx.x * 256 + threadIdx.x;
    if (i >= 32 * 4 * HW) return;
    int o = (i / HW) & 3;
    float z = fmaxf(raw[i] + ab[o], 0.f);
    attn[i] = 1.f / (1.f + expf(-z));
}

// ---------------- K2: per-channel BN partial sums of xh = x*attn ----------
__global__ __launch_bounds__(256)
void k2_stats(const float* __restrict__ x, const float* __restrict__ attn,
              float* __restrict__ bn_sum, float* __restrict__ bn_sumsq) {
    const int c  = blockIdx.x & 255;
    const int bt = blockIdx.x >> 8;
    const int head = c >> 6;
    const float4* xp = (const float4*)(x + ((size_t)bt * CC + c) * HW);
    const float4* ap = (const float4*)(attn + ((size_t)bt * 4 + head) * HW);
    float s = 0.f, s2 = 0.f;
    for (int i = threadIdx.x; i < HW / 4; i += 256) {
        float4 xv = xp[i], av = ap[i];
        float v0 = xv.x * av.x, v1 = xv.y * av.y, v2 = xv.z * av.z, v3 = xv.w * av.w;
        s  += v0 + v1 + v2 + v3;
        s2 += v0 * v0 + v1 * v1 + v2 * v2 + v3 * v3;
    }
    #pragma unroll
    for (int off = 32; off > 0; off >>= 1) {
        s  += __shfl_down(s, off);
        s2 += __shfl_down(s2, off);
    }
    __shared__ float red[8];
    const int wave = threadIdx.x >> 6;
    if ((threadIdx.x & 63) == 0) { red[wave * 2] = s; red[wave * 2 + 1] = s2; }
    __syncthreads();
    if (threadIdx.x == 0) {
        atomicAdd(&bn_sum[c],   red[0] + red[2] + red[4] + red[6]);
        atomicAdd(&bn_sumsq[c], red[1] + red[3] + red[5] + red[7]);
    }
}

// ---------------- K3: finalize BN -> per-channel scale/shift --------------
__global__ void k3_final(const float* __restrict__ bn_sum, const float* __restrict__ bn_sumsq,
                         const float* __restrict__ gamma, const float* __restrict__ beta,
                         float* __restrict__ scale, float* __restrict__ shift) {
    int c = threadIdx.x;
    const float invN = 1.f / 100352.f;            // B*T*H*W
    float mean = bn_sum[c] * invN;
    float var  = bn_sumsq[c] * invN - mean * mean;
    float sc   = gamma[c] * rsqrtf(var + 1e-5f);
    scale[c] = sc;
    shift[c] = fmaf(-mean, sc, beta[c]);
}

// ---------------- K4: grouped dilated conv3d, LDS-staged, double-buffered -
__global__ __launch_bounds__(256)
void k4_gate(const float* __restrict__ x, const float* __restrict__ attn,
             const float* __restrict__ scale, const float* __restrict__ shift,
             const float* __restrict__ gw0, const float* __restrict__ gw1,
             float* __restrict__ gate_raw) {
    const int blk   = blockIdx.x;
    const int chunk = blk & 31;             // 32 chunks x 8 channels
    const int ht    = (blk >> 5) % 14;
    const int b     = blk / (32 * 14);
    const int h0    = ht * 4;
    const int g     = chunk >> 4;           // group: ch 0..127 -> 0, else 1
    const int head  = chunk >> 3;           // 8-ch chunk sits inside one head
    __shared__ float tile[2][TT * 6 * 58];  // 22272 B
    float* tf = &tile[0][0];
    const int tid = threadIdx.x;

    // per-thread staging descriptors (channel-independent), elems 2784
    int   soff[11];
    int   goff[11];
    float av[11];
    bool  vld[11];
    #pragma unroll
    for (int k = 0; k < 11; ++k) {
        int idx = tid + k * 256;
        bool in = idx < TT * 6 * 58;
        int t   = idx / 348;
        int rem = idx - t * 348;
        int r   = rem / 58;
        int col = rem - r * 58;
        int gh = h0 + r - 1, gw = col - 1;
        bool v = in && (unsigned)gh < HH && (unsigned)gw < WW;
        vld[k]  = v;
        soff[k] = idx;
        goff[k] = ((b * 8 + t) * CC) * HW + gh * WW + gw;
        av[k]   = v ? attn[((size_t)(b * 8 + t) * 4 + head) * HW + gh * WW + gw] : 0.f;
        if (in && !v) { tf[idx] = 0.f; tf[2784 + idx] = 0.f; }
    }

    {
        const int c0 = chunk * 8;
        const float sc = scale[c0], sh = shift[c0];
        #pragma unroll
        for (int k = 0; k < 11; ++k)
            if (vld[k]) {
                float xv = x[(size_t)goff[k] + (size_t)c0 * HW];
                tf[soff[k]] = fmaxf(fmaf(xv * av[k], sc, sh), 0.f);
            }
    }
    __syncthreads();

    const int wc = tid % WW;
    const int hr = tid / WW;
    const bool active = tid < 4 * WW;
    float acc[2][8];
    #pragma unroll
    for (int d = 0; d < 2; ++d)
        #pragma unroll
        for (int t = 0; t < 8; ++t) acc[d][t] = 0.f;

    for (int cl = 0; cl < 8; ++cl) {
        const int c = chunk * 8 + cl;
        float xv[11];
        if (cl < 7) {
            #pragma unroll
            for (int k = 0; k < 11; ++k)
                xv[k] = vld[k] ? x[(size_t)goff[k] + (size_t)(c + 1) * HW] : 0.f;
        }
        if (active) {
            const float* buf = tf + (cl & 1) * 2784;
            const int ci = c & 127;
            const float* wp0 = gw0 + ((size_t)g * 128 + ci) * 27;
            const float* wp1 = gw1 + ((size_t)g * 128 + ci) * 27;
            #pragma unroll
            for (int t = 0; t < 8; ++t) {
                float v[9];
                #pragma unroll
                for (int ki = 0; ki < 3; ++ki)
                    #pragma unroll
                    for (int kj = 0; kj < 3; ++kj)
                        v[ki * 3 + kj] = buf[t * 348 + (hr + ki) * 58 + wc + kj];
                #pragma unroll
                for (int kd = 0; kd < 3; ++kd) {
                    {
                        const int to = t + 1 - kd;
                        if (to >= 0 && to < 8) {
                            float s = 0.f;
                            #pragma unroll
                            for (int k = 0; k < 9; ++k) s = fmaf(wp0[kd * 9 + k], v[k], s);
                            acc[0][to] += s;
                        }
                    }
                    {
                        const int to = t + 2 - 2 * kd;
                        if (to >= 0 && to < 8) {
                            float s = 0.f;
                            #pragma unroll
                            for (int k = 0; k < 9; ++k) s = fmaf(wp1[kd * 9 + k], v[k], s);
                            acc[1][to] += s;
                        }
                    }
                }
            }
        }
        if (cl < 7) {
            const float scn = scale[c + 1], shn = shift[c + 1];
            float* bufn = tf + ((cl + 1) & 1) * 2784;
            #pragma unroll
            for (int k = 0; k < 11; ++k)
                if (vld[k])
                    bufn[soff[k]] = fmaxf(fmaf(xv[k] * av[k], scn, shn), 0.f);
        }
        __syncthreads();
    }

    if (active) {
        const int hw = (h0 + hr) * WW + wc;
        #pragma unroll
        for (int d = 0; d < 2; ++d)
            #pragma unroll
            for (int t = 0; t < 8; ++t)
                atomicAdd(&gate_raw[(((size_t)(d * 4 + b) * 2 + g) * 8 + t) * HW + hw],
                          acc[d][t]);
    }
}

// ---------------- K4b: gate = tanh(raw + bias) ----------------------------
__global__ void k4b_tanh(const float* __restrict__ raw, const float* __restrict__ gb0,
                         const float* __restrict__ gb1, float* __restrict__ gt) {
    int i = blockIdx.x * 256 + threadIdx.x;
    if (i >= 401408) return;
    int d   = i / 200704;
    int rem = i - d * 200704;
    int g   = (rem / 25088) & 1;
    float bias = (d == 0) ? gb0[g] : gb1[g];
    gt[i] = tanhf(raw[i] + bias);
}

// ---------------- K5: fuse + shuffle + alpha-combine ----------------------
__global__ __launch_bounds__(256)
void k5_fuse(const float* __restrict__ x, const float* __restrict__ attn,
             const float* __restrict__ scale, const float* __restrict__ shift,
             const float* __restrict__ gt, const float* __restrict__ alpha,
             float* __restrict__ out) {
    const int blk  = blockIdx.x;
    const int tile = blk % 13;
    const int c    = (blk / 13) & 255;
    const int b    = blk / (13 * 256);
    const int hw   = tile * 256 + threadIdx.x;
    if (hw >= HW) return;
    const int clo  = c & 127;
    const int cs   = (c & 128) | ((clo & 1) << 6) | (clo >> 1);  // inverse shuffle
    const int g    = c >> 7;
    const int head = cs >> 6;
    const float sc = scale[cs], sh = shift[cs];
    float xr[8], G0[8], G1[8];
    #pragma unroll
    for (int t = 0; t < 8; ++t) {
        const int bti = b * 8 + t;
        float xv = x[((size_t)bti * CC + cs) * HW + hw];
        float av = attn[((size_t)bti * 4 + head) * HW + hw];
        xr[t] = fmaxf(fmaf(xv * av, sc, sh), 0.f);
        G0[t] = gt[(((size_t)(0 * 4 + b) * 2 + g) * 8 + t) * HW + hw];
        G1[t] = gt[(((size_t)(1 * 4 + b) * 2 + g) * 8 + t) * HW + hw];
    }
    const float a0 = alpha[0], a1 = alpha[1];
    #pragma unroll
    for (int t = 0; t < 8; ++t) {
        float v0, v1;
        if (g == 0) {
            v0 = xr[t] * (1.f - G0[t]) + (t + 1 < 8 ? G0[t + 1] * xr[t + 1] : 0.f);
            v1 = xr[t] * (1.f - G1[t]) + (t + 2 < 8 ? G1[t + 2] * xr[t + 2] : 0.f);
        } else {
            v0 = xr[t] * (1.f - G0[t]) + (t - 1 >= 0 ? G0[t - 1] * xr[t - 1] : 0.f);
            v1 = xr[t] * (1.f - G1[t]) + (t - 2 >= 0 ? G1[t - 2] * xr[t - 2] : 0.f);
        }
        out[((size_t)(b * 8 + t) * CC + c) * HW + hw] = fmaf(a0, v0, a1 * v1);
    }
}

extern "C" void kernel_launch(void* const* d_in, const int* in_sizes, int n_in,
                              void* d_out, int out_size, void* d_ws, size_t ws_size,
                              hipStream_t stream) {
    const float* x     = (const float*)d_in[0];
    const float* aw    = (const float*)d_in[1];
    const float* ab    = (const float*)d_in[2];
    const float* gamma = (const float*)d_in[3];
    const float* beta  = (const float*)d_in[4];
    const float* gw0   = (const float*)d_in[5];
    const float* gb0   = (const float*)d_in[6];
    const float* gw1   = (const float*)d_in[7];
    const float* gb1   = (const float*)d_in[8];
    const float* alpha = (const float*)d_in[9];
    float* out = (float*)d_out;
    float* ws  = (float*)d_ws;

    // ws layout (floats):
    //   [gate_raw 401408 | attn_raw/gate_t 401408 | bn_sum 256 | bn_sumsq 256 |
    //    attn 401408 | scale 256 | shift 256]
    float* gate_raw = ws;
    float* attn_raw = ws + 401408;
    float* gate_t   = attn_raw;             // alias (timeline-disjoint)
    float* bn_sum   = ws + 802816;
    float* bn_sumsq = ws + 803072;
    float* attn     = ws + 803328;
    float* scale    = ws + 1204736;
    float* shift    = ws + 1204992;

    // zero all atomic-accumulated regions in one memset (contiguous prefix)
    hipMemsetAsync(ws, 0, (size_t)(401408 + 401408 + 512) * sizeof(float), stream);

    k1_attn <<<dim3(1792),  dim3(128), 0, stream>>>(x, aw, attn_raw);
    k1b_act <<<dim3(1568),  dim3(256), 0, stream>>>(attn_raw, ab, attn);
    k2_stats<<<dim3(8192),  dim3(256), 0, stream>>>(x, attn, bn_sum, bn_sumsq);
    k3_final<<<dim3(1),     dim3(256), 0, stream>>>(bn_sum, bn_sumsq, gamma, beta, scale, shift);
    k4_gate <<<dim3(1792),  dim3(256), 0, stream>>>(x, attn, scale, shift, gw0, gw1, gate_raw);
    k4b_tanh<<<dim3(1568),  dim3(256), 0, stream>>>(gate_raw, gb0, gb1, gate_t);
    k5_fuse <<<dim3(13312), dim3(256), 0, stream>>>(x, attn, scale, shift, gate_t, alpha, out);
}

// Round 8
// 218.079 us; speedup vs baseline: 1.6105x; 1.0855x over previous
//
#include <hip/hip_runtime.h>
#include <math.h>

#define HH 56
#define WW 56
#define CC 256
#define TT 8
#define HW 3136

// ---------------- K1: attn partial conv2d, float2-pair per thread ---------
// grid = bt(32) x csplit(8 of 32ch) x ptile(7 of 256 pairs) = 1792 blocks,
// block = 256 (4 waves) -> 7168 waves = 7/SIMD (quad version was 3.5/SIMD,
// wave-starved: VALUBusy 18.6%). Thread owns 2 output cols (float2 pair).
// Per channel: 3x(float2 + 2 halo scalars) = 9 loads feed 72 FMAs (8:1).
__global__ __launch_bounds__(256)
void k1_attn(const float* __restrict__ x, const float* __restrict__ aw,
             float* __restrict__ attn_raw) {
    const int blk   = blockIdx.x;
    const int cs    = blk & 7;
    const int ptile = (blk >> 3) % 7;
    const int bt    = blk / 56;
    const int pi    = ptile * 256 + threadIdx.x;   // 0..1791, active < 1568
    if (pi >= 1568) return;
    const int row  = pi / 28;
    const int pc   = pi - row * 28;
    const int col0 = pc * 2;
    const bool okm = row > 0, okp = row < HH - 1;
    const bool okl = pc > 0,  okr = pc < 27;
    const int base  = row * WW + col0;
    const int basem = okm ? base - WW : base;    // clamped (safe) addresses
    const int basep = okp ? base + WW : base;
    const float* xb = x + ((size_t)bt * CC + cs * 32) * HW;

    float acc[4][2];
    #pragma unroll
    for (int h = 0; h < 4; ++h) { acc[h][0] = 0.f; acc[h][1] = 0.f; }

    #pragma unroll 2
    for (int cl = 0; cl < 32; ++cl) {
        const int c = cs * 32 + cl;
        const float* xp = xb + (size_t)cl * HW;
        float2 Cm = *(const float2*)(xp + basem);
        float  Lm = okl ? xp[basem - 1] : 0.f;
        float  Rm = okr ? xp[basem + 2] : 0.f;
        float2 Cc = *(const float2*)(xp + base);
        float  Lc = okl ? xp[base - 1] : 0.f;
        float  Rc = okr ? xp[base + 2] : 0.f;
        float2 Cp = *(const float2*)(xp + basep);
        float  Lp = okl ? xp[basep - 1] : 0.f;
        float  Rp = okr ? xp[basep + 2] : 0.f;
        if (!okm) { Cm.x = 0.f; Cm.y = 0.f; Lm = 0.f; Rm = 0.f; }
        if (!okp) { Cp.x = 0.f; Cp.y = 0.f; Lp = 0.f; Rp = 0.f; }

        #pragma unroll
        for (int h = 0; h < 4; ++h) {
            const float* w = aw + ((size_t)h * CC + c) * 9;
            const float w0 = w[0], w1 = w[1], w2 = w[2];
            const float w3 = w[3], w4 = w[4], w5 = w[5];
            const float w6 = w[6], w7 = w[7], w8 = w[8];
            acc[h][0] = fmaf(w0, Lm,   fmaf(w1, Cm.x, fmaf(w2, Cm.y,
                        fmaf(w3, Lc,   fmaf(w4, Cc.x, fmaf(w5, Cc.y,
                        fmaf(w6, Lp,   fmaf(w7, Cp.x, fmaf(w8, Cp.y, acc[h][0])))))))));
            acc[h][1] = fmaf(w0, Cm.x, fmaf(w1, Cm.y, fmaf(w2, Rm,
                        fmaf(w3, Cc.x, fmaf(w4, Cc.y, fmaf(w5, Rc,
                        fmaf(w6, Cp.x, fmaf(w7, Cp.y, fmaf(w8, Rp, acc[h][1])))))))));
        }
    }
    #pragma unroll
    for (int h = 0; h < 4; ++h) {
        atomicAdd(&attn_raw[((size_t)bt * 4 + h) * HW + base + 0], acc[h][0]);
        atomicAdd(&attn_raw[((size_t)bt * 4 + h) * HW + base + 1], acc[h][1]);
    }
}

// ---------------- K1b: attn = sigmoid(relu(raw + bias)) -------------------
__global__ void k1b_act(const float* __restrict__ raw, const float* __restrict__ ab,
                        float* __restrict__ attn) {
    int i = blockIdx.x * 256 + threadIdx.x;
    if (i >= 32 * 4 * HW) return;
    int o = (i / HW) & 3;
    float z = fmaxf(raw[i] + ab[o], 0.f);
    attn[i] = 1.f / (1.f + expf(-z));
}

// ---------------- K2: per-channel BN partial sums of xh = x*attn ----------
__global__ __launch_bounds__(256)
void k2_stats(const float* __restrict__ x, const float* __restrict__ attn,
              float* __restrict__ bn_sum, float* __restrict__ bn_sumsq) {
    const int c  = blockIdx.x & 255;
    const int bt = blockIdx.x >> 8;
    const int head = c >> 6;
    const float4* xp = (const float4*)(x + ((size_t)bt * CC + c) * HW);
    const float4* ap = (const float4*)(attn + ((size_t)bt * 4 + head) * HW);
    float s = 0.f, s2 = 0.f;
    for (int i = threadIdx.x; i < HW / 4; i += 256) {
        float4 xv = xp[i], av = ap[i];
        float v0 = xv.x * av.x, v1 = xv.y * av.y, v2 = xv.z * av.z, v3 = xv.w * av.w;
        s  += v0 + v1 + v2 + v3;
        s2 += v0 * v0 + v1 * v1 + v2 * v2 + v3 * v3;
    }
    #pragma unroll
    for (int off = 32; off > 0; off >>= 1) {
        s  += __shfl_down(s, off);
        s2 += __shfl_down(s2, off);
    }
    __shared__ float red[8];
    const int wave = threadIdx.x >> 6;
    if ((threadIdx.x & 63) == 0) { red[wave * 2] = s; red[wave * 2 + 1] = s2; }
    __syncthreads();
    if (threadIdx.x == 0) {
        atomicAdd(&bn_sum[c],   red[0] + red[2] + red[4] + red[6]);
        atomicAdd(&bn_sumsq[c], red[1] + red[3] + red[5] + red[7]);
    }
}

// ---------------- K3: finalize BN -> per-channel scale/shift --------------
__global__ void k3_final(const float* __restrict__ bn_sum, const float* __restrict__ bn_sumsq,
                         const float* __restrict__ gamma, const float* __restrict__ beta,
                         float* __restrict__ scale, float* __restrict__ shift) {
    int c = threadIdx.x;
    const float invN = 1.f / 100352.f;            // B*T*H*W
    float mean = bn_sum[c] * invN;
    float var  = bn_sumsq[c] * invN - mean * mean;
    float sc   = gamma[c] * rsqrtf(var + 1e-5f);
    scale[c] = sc;
    shift[c] = fmaf(-mean, sc, beta[c]);
}

// ---------------- K4: grouped dilated conv3d, LDS-staged, double-buffered -
__global__ __launch_bounds__(256)
void k4_gate(const float* __restrict__ x, const float* __restrict__ attn,
             const float* __restrict__ scale, const float* __restrict__ shift,
             const float* __restrict__ gw0, const float* __restrict__ gw1,
             float* __restrict__ gate_raw) {
    const int blk   = blockIdx.x;
    const int chunk = blk & 31;             // 32 chunks x 8 channels
    const int ht    = (blk >> 5) % 14;
    const int b     = blk / (32 * 14);
    const int h0    = ht * 4;
    const int g     = chunk >> 4;           // group: ch 0..127 -> 0, else 1
    const int head  = chunk >> 3;           // 8-ch chunk sits inside one head
    __shared__ float tile[2][TT * 6 * 58];  // 22272 B
    float* tf = &tile[0][0];
    const int tid = threadIdx.x;

    // per-thread staging descriptors (channel-independent), elems 2784
    int   soff[11];
    int   goff[11];
    float av[11];
    bool  vld[11];
    #pragma unroll
    for (int k = 0; k < 11; ++k) {
        int idx = tid + k * 256;
        bool in = idx < TT * 6 * 58;
        int t   = idx / 348;
        int rem = idx - t * 348;
        int r   = rem / 58;
        int col = rem - r * 58;
        int gh = h0 + r - 1, gw = col - 1;
        bool v = in && (unsigned)gh < HH && (unsigned)gw < WW;
        vld[k]  = v;
        soff[k] = idx;
        goff[k] = ((b * 8 + t) * CC) * HW + gh * WW + gw;
        av[k]   = v ? attn[((size_t)(b * 8 + t) * 4 + head) * HW + gh * WW + gw] : 0.f;
        if (in && !v) { tf[idx] = 0.f; tf[2784 + idx] = 0.f; }
    }

    {
        const int c0 = chunk * 8;
        const float sc = scale[c0], sh = shift[c0];
        #pragma unroll
        for (int k = 0; k < 11; ++k)
            if (vld[k]) {
                float xv = x[(size_t)goff[k] + (size_t)c0 * HW];
                tf[soff[k]] = fmaxf(fmaf(xv * av[k], sc, sh), 0.f);
            }
    }
    __syncthreads();

    const int wc = tid % WW;
    const int hr = tid / WW;
    const bool active = tid < 4 * WW;
    float acc[2][8];
    #pragma unroll
    for (int d = 0; d < 2; ++d)
        #pragma unroll
        for (int t = 0; t < 8; ++t) acc[d][t] = 0.f;

    for (int cl = 0; cl < 8; ++cl) {
        const int c = chunk * 8 + cl;
        float xv[11];
        if (cl < 7) {
            #pragma unroll
            for (int k = 0; k < 11; ++k)
                xv[k] = vld[k] ? x[(size_t)goff[k] + (size_t)(c + 1) * HW] : 0.f;
        }
        if (active) {
            const float* buf = tf + (cl & 1) * 2784;
            const int ci = c & 127;
            const float* wp0 = gw0 + ((size_t)g * 128 + ci) * 27;
            const float* wp1 = gw1 + ((size_t)g * 128 + ci) * 27;
            #pragma unroll
            for (int t = 0; t < 8; ++t) {
                float v[9];
                #pragma unroll
                for (int ki = 0; ki < 3; ++ki)
                    #pragma unroll
                    for (int kj = 0; kj < 3; ++kj)
                        v[ki * 3 + kj] = buf[t * 348 + (hr + ki) * 58 + wc + kj];
                #pragma unroll
                for (int kd = 0; kd < 3; ++kd) {
                    {
                        const int to = t + 1 - kd;
                        if (to >= 0 && to < 8) {
                            float s = 0.f;
                            #pragma unroll
                            for (int k = 0; k < 9; ++k) s = fmaf(wp0[kd * 9 + k], v[k], s);
                            acc[0][to] += s;
                        }
                    }
                    {
                        const int to = t + 2 - 2 * kd;
                        if (to >= 0 && to < 8) {
                            float s = 0.f;
                            #pragma unroll
                            for (int k = 0; k < 9; ++k) s = fmaf(wp1[kd * 9 + k], v[k], s);
                            acc[1][to] += s;
                        }
                    }
                }
            }
        }
        if (cl < 7) {
            const float scn = scale[c + 1], shn = shift[c + 1];
            float* bufn = tf + ((cl + 1) & 1) * 2784;
            #pragma unroll
            for (int k = 0; k < 11; ++k)
                if (vld[k])
                    bufn[soff[k]] = fmaxf(fmaf(xv[k] * av[k], scn, shn), 0.f);
        }
        __syncthreads();
    }

    if (active) {
        const int hw = (h0 + hr) * WW + wc;
        #pragma unroll
        for (int d = 0; d < 2; ++d)
            #pragma unroll
            for (int t = 0; t < 8; ++t)
                atomicAdd(&gate_raw[(((size_t)(d * 4 + b) * 2 + g) * 8 + t) * HW + hw],
                          acc[d][t]);
    }
}

// ---------------- K4b: gate = tanh(raw + bias) ----------------------------
__global__ void k4b_tanh(const float* __restrict__ raw, const float* __restrict__ gb0,
                         const float* __restrict__ gb1, float* __restrict__ gt) {
    int i = blockIdx.x * 256 + threadIdx.x;
    if (i >= 401408) return;
    int d   = i / 200704;
    int rem = i - d * 200704;
    int g   = (rem / 25088) & 1;
    float bias = (d == 0) ? gb0[g] : gb1[g];
    gt[i] = tanhf(raw[i] + bias);
}

// ---------------- K5: fuse + shuffle + alpha-combine ----------------------
__global__ __launch_bounds__(256)
void k5_fuse(const float* __restrict__ x, const float* __restrict__ attn,
             const float* __restrict__ scale, const float* __restrict__ shift,
             const float* __restrict__ gt, const float* __restrict__ alpha,
             float* __restrict__ out) {
    const int blk  = blockIdx.x;
    const int tile = blk % 13;
    const int c    = (blk / 13) & 255;
    const int b    = blk / (13 * 256);
    const int hw   = tile * 256 + threadIdx.x;
    if (hw >= HW) return;
    const int clo  = c & 127;
    const int cs   = (c & 128) | ((clo & 1) << 6) | (clo >> 1);  // inverse shuffle
    const int g    = c >> 7;
    const int head = cs >> 6;
    const float sc = scale[cs], sh = shift[cs];
    float xr[8], G0[8], G1[8];
    #pragma unroll
    for (int t = 0; t < 8; ++t) {
        const int bti = b * 8 + t;
        float xv = x[((size_t)bti * CC + cs) * HW + hw];
        float av = attn[((size_t)bti * 4 + head) * HW + hw];
        xr[t] = fmaxf(fmaf(xv * av, sc, sh), 0.f);
        G0[t] = gt[(((size_t)(0 * 4 + b) * 2 + g) * 8 + t) * HW + hw];
        G1[t] = gt[(((size_t)(1 * 4 + b) * 2 + g) * 8 + t) * HW + hw];
    }
    const float a0 = alpha[0], a1 = alpha[1];
    #pragma unroll
    for (int t = 0; t < 8; ++t) {
        float v0, v1;
        if (g == 0) {
            v0 = xr[t] * (1.f - G0[t]) + (t + 1 < 8 ? G0[t + 1] * xr[t + 1] : 0.f);
            v1 = xr[t] * (1.f - G1[t]) + (t + 2 < 8 ? G1[t + 2] * xr[t + 2] : 0.f);
        } else {
            v0 = xr[t] * (1.f - G0[t]) + (t - 1 >= 0 ? G0[t - 1] * xr[t - 1] : 0.f);
            v1 = xr[t] * (1.f - G1[t]) + (t - 2 >= 0 ? G1[t - 2] * xr[t - 2] : 0.f);
        }
        out[((size_t)(b * 8 + t) * CC + c) * HW + hw] = fmaf(a0, v0, a1 * v1);
    }
}

extern "C" void kernel_launch(void* const* d_in, const int* in_sizes, int n_in,
                              void* d_out, int out_size, void* d_ws, size_t ws_size,
                              hipStream_t stream) {
    const float* x     = (const float*)d_in[0];
    const float* aw    = (const float*)d_in[1];
    const float* ab    = (const float*)d_in[2];
    const float* gamma = (const float*)d_in[3];
    const float* beta  = (const float*)d_in[4];
    const float* gw0   = (const float*)d_in[5];
    const float* gb0   = (const float*)d_in[6];
    const float* gw1   = (const float*)d_in[7];
    const float* gb1   = (const float*)d_in[8];
    const float* alpha = (const float*)d_in[9];
    float* out = (float*)d_out;
    float* ws  = (float*)d_ws;

    // ws layout (floats):
    //   [gate_raw 401408 | attn_raw/gate_t 401408 | bn_sum 256 | bn_sumsq 256 |
    //    attn 401408 | scale 256 | shift 256]
    float* gate_raw = ws;
    float* attn_raw = ws + 401408;
    float* gate_t   = attn_raw;             // alias (timeline-disjoint)
    float* bn_sum   = ws + 802816;
    float* bn_sumsq = ws + 803072;
    float* attn     = ws + 803328;
    float* scale    = ws + 1204736;
    float* shift    = ws + 1204992;

    // zero all atomic-accumulated regions in one memset (contiguous prefix)
    hipMemsetAsync(ws, 0, (size_t)(401408 + 401408 + 512) * sizeof(float), stream);

    k1_attn <<<dim3(1792),  dim3(256), 0, stream>>>(x, aw, attn_raw);
    k1b_act <<<dim3(1568),  dim3(256), 0, stream>>>(attn_raw, ab, attn);
    k2_stats<<<dim3(8192),  dim3(256), 0, stream>>>(x, attn, bn_sum, bn_sumsq);
    k3_final<<<dim3(1),     dim3(256), 0, stream>>>(bn_sum, bn_sumsq, gamma, beta, scale, shift);
    k4_gate <<<dim3(1792),  dim3(256), 0, stream>>>(x, attn, scale, shift, gw0, gw1, gate_raw);
    k4b_tanh<<<dim3(1568),  dim3(256), 0, stream>>>(gate_raw, gb0, gb1, gate_t);
    k5_fuse <<<dim3(13312), dim3(256), 0, stream>>>(x, attn, scale, shift, gate_t, alpha, out);
}

// Round 9
// 213.353 us; speedup vs baseline: 1.6462x; 1.0222x over previous
//
#include <hip/hip_runtime.h>
#include <math.h>

#define HH 56
#define WW 56
#define CC 256
#define TT 8
#define HW 3136

// ---------------- K1: attn conv2d, LDS-staged, double-buffered ------------
// Ported to the proven k4 structure (round 4). grid = bt(32) x 4-row
// band(14) x csplit(4 of 64ch) = 1792 blocks. Per channel: stage 6x58 raw-x
// tile into LDS (halo zeros = conv zero-padding), reg-prefetch next channel,
// ONE barrier per channel. 224 active threads: 9 ds_reads -> 4 heads x 9 FMA.
// Weights wave-uniform -> scalar loads. Direct-global k1 variants were all
// VMEM-bound (9 scattered loads/thread/channel); this stages each plane once.
__global__ __launch_bounds__(256)
void k1_attn(const float* __restrict__ x, const float* __restrict__ aw,
             float* __restrict__ attn_raw) {
    const int blk = blockIdx.x;
    const int cs  = blk & 3;
    const int ht  = (blk >> 2) % 14;
    const int bt  = blk / 56;
    const int h0  = ht * 4;
    __shared__ float tile[2][6 * 58];       // 2784 B
    float* tf = &tile[0][0];
    const int tid = threadIdx.x;
    const float* xb = x + ((size_t)bt * CC + cs * 64) * HW;

    // per-thread staging descriptors (channel-independent), 348 elems
    int  soff[2], goff[2];
    bool vld[2];
    #pragma unroll
    for (int k = 0; k < 2; ++k) {
        int idx = tid + k * 256;
        bool in = idx < 6 * 58;
        int r   = idx / 58;
        int col = idx - r * 58;
        int gh = h0 + r - 1, gw = col - 1;
        bool v = in && (unsigned)gh < HH && (unsigned)gw < WW;
        vld[k]  = v;
        soff[k] = idx;
        goff[k] = gh * WW + gw;
        if (in && !v) { tf[idx] = 0.f; tf[348 + idx] = 0.f; }  // zero halo once
    }

    // stage channel 0 into buffer 0
    #pragma unroll
    for (int k = 0; k < 2; ++k)
        if (vld[k]) tf[soff[k]] = xb[goff[k]];
    __syncthreads();

    const int wc = tid % WW;
    const int hr = tid / WW;
    const bool active = tid < 4 * WW;
    float acc[4] = {0.f, 0.f, 0.f, 0.f};

    for (int cl = 0; cl < 64; ++cl) {
        // prefetch next channel into regs (latency hidden under compute)
        float xv[2];
        if (cl < 63) {
            #pragma unroll
            for (int k = 0; k < 2; ++k)
                xv[k] = vld[k] ? xb[(size_t)(cl + 1) * HW + goff[k]] : 0.f;
        }
        // compute current channel from LDS buffer (cl&1)
        if (active) {
            const float* buf = tf + (cl & 1) * 348;
            float v[9];
            #pragma unroll
            for (int ki = 0; ki < 3; ++ki)
                #pragma unroll
                for (int kj = 0; kj < 3; ++kj)
                    v[ki * 3 + kj] = buf[(hr + ki) * 58 + wc + kj];
            const int c = cs * 64 + cl;
            #pragma unroll
            for (int h = 0; h < 4; ++h) {
                const float* w = aw + ((size_t)h * CC + c) * 9;
                float s = 0.f;
                #pragma unroll
                for (int k = 0; k < 9; ++k) s = fmaf(w[k], v[k], s);
                acc[h] += s;
            }
        }
        // write prefetched channel into the other buffer
        if (cl < 63) {
            float* bufn = tf + ((cl + 1) & 1) * 348;
            #pragma unroll
            for (int k = 0; k < 2; ++k)
                if (vld[k]) bufn[soff[k]] = xv[k];
        }
        __syncthreads();
    }

    if (active) {
        const int base = (h0 + hr) * WW + wc;
        #pragma unroll
        for (int h = 0; h < 4; ++h)
            atomicAdd(&attn_raw[((size_t)bt * 4 + h) * HW + base], acc[h]);
    }
}

// ---------------- K1b: attn = sigmoid(relu(raw + bias)) -------------------
__global__ void k1b_act(const float* __restrict__ raw, const float* __restrict__ ab,
                        float* __restrict__ attn) {
    int i = blockIdx.x * 256 + threadIdx.x;
    if (i >= 32 * 4 * HW) return;
    int o = (i / HW) & 3;
    float z = fmaxf(raw[i] + ab[o], 0.f);
    attn[i] = 1.f / (1.f + expf(-z));
}

// ---------------- K2: per-channel BN partial sums of xh = x*attn ----------
__global__ __launch_bounds__(256)
void k2_stats(const float* __restrict__ x, const float* __restrict__ attn,
              float* __restrict__ bn_sum, float* __restrict__ bn_sumsq) {
    const int c  = blockIdx.x & 255;
    const int bt = blockIdx.x >> 8;
    const int head = c >> 6;
    const float4* xp = (const float4*)(x + ((size_t)bt * CC + c) * HW);
    const float4* ap = (const float4*)(attn + ((size_t)bt * 4 + head) * HW);
    float s = 0.f, s2 = 0.f;
    for (int i = threadIdx.x; i < HW / 4; i += 256) {
        float4 xv = xp[i], av = ap[i];
        float v0 = xv.x * av.x, v1 = xv.y * av.y, v2 = xv.z * av.z, v3 = xv.w * av.w;
        s  += v0 + v1 + v2 + v3;
        s2 += v0 * v0 + v1 * v1 + v2 * v2 + v3 * v3;
    }
    #pragma unroll
    for (int off = 32; off > 0; off >>= 1) {
        s  += __shfl_down(s, off);
        s2 += __shfl_down(s2, off);
    }
    __shared__ float red[8];
    const int wave = threadIdx.x >> 6;
    if ((threadIdx.x & 63) == 0) { red[wave * 2] = s; red[wave * 2 + 1] = s2; }
    __syncthreads();
    if (threadIdx.x == 0) {
        atomicAdd(&bn_sum[c],   red[0] + red[2] + red[4] + red[6]);
        atomicAdd(&bn_sumsq[c], red[1] + red[3] + red[5] + red[7]);
    }
}

// ---------------- K3: finalize BN -> per-channel scale/shift --------------
__global__ void k3_final(const float* __restrict__ bn_sum, const float* __restrict__ bn_sumsq,
                         const float* __restrict__ gamma, const float* __restrict__ beta,
                         float* __restrict__ scale, float* __restrict__ shift) {
    int c = threadIdx.x;
    const float invN = 1.f / 100352.f;            // B*T*H*W
    float mean = bn_sum[c] * invN;
    float var  = bn_sumsq[c] * invN - mean * mean;
    float sc   = gamma[c] * rsqrtf(var + 1e-5f);
    scale[c] = sc;
    shift[c] = fmaf(-mean, sc, beta[c]);
}

// ---------------- K4: grouped dilated conv3d, LDS-staged, double-buffered -
__global__ __launch_bounds__(256)
void k4_gate(const float* __restrict__ x, const float* __restrict__ attn,
             const float* __restrict__ scale, const float* __restrict__ shift,
             const float* __restrict__ gw0, const float* __restrict__ gw1,
             float* __restrict__ gate_raw) {
    const int blk   = blockIdx.x;
    const int chunk = blk & 31;             // 32 chunks x 8 channels
    const int ht    = (blk >> 5) % 14;
    const int b     = blk / (32 * 14);
    const int h0    = ht * 4;
    const int g     = chunk >> 4;           // group: ch 0..127 -> 0, else 1
    const int head  = chunk >> 3;           // 8-ch chunk sits inside one head
    __shared__ float tile[2][TT * 6 * 58];  // 22272 B
    float* tf = &tile[0][0];
    const int tid = threadIdx.x;

    // per-thread staging descriptors (channel-independent), elems 2784
    int   soff[11];
    int   goff[11];
    float av[11];
    bool  vld[11];
    #pragma unroll
    for (int k = 0; k < 11; ++k) {
        int idx = tid + k * 256;
        bool in = idx < TT * 6 * 58;
        int t   = idx / 348;
        int rem = idx - t * 348;
        int r   = rem / 58;
        int col = rem - r * 58;
        int gh = h0 + r - 1, gw = col - 1;
        bool v = in && (unsigned)gh < HH && (unsigned)gw < WW;
        vld[k]  = v;
        soff[k] = idx;
        goff[k] = ((b * 8 + t) * CC) * HW + gh * WW + gw;
        av[k]   = v ? attn[((size_t)(b * 8 + t) * 4 + head) * HW + gh * WW + gw] : 0.f;
        if (in && !v) { tf[idx] = 0.f; tf[2784 + idx] = 0.f; }
    }

    {
        const int c0 = chunk * 8;
        const float sc = scale[c0], sh = shift[c0];
        #pragma unroll
        for (int k = 0; k < 11; ++k)
            if (vld[k]) {
                float xv = x[(size_t)goff[k] + (size_t)c0 * HW];
                tf[soff[k]] = fmaxf(fmaf(xv * av[k], sc, sh), 0.f);
            }
    }
    __syncthreads();

    const int wc = tid % WW;
    const int hr = tid / WW;
    const bool active = tid < 4 * WW;
    float acc[2][8];
    #pragma unroll
    for (int d = 0; d < 2; ++d)
        #pragma unroll
        for (int t = 0; t < 8; ++t) acc[d][t] = 0.f;

    for (int cl = 0; cl < 8; ++cl) {
        const int c = chunk * 8 + cl;
        float xv[11];
        if (cl < 7) {
            #pragma unroll
            for (int k = 0; k < 11; ++k)
                xv[k] = vld[k] ? x[(size_t)goff[k] + (size_t)(c + 1) * HW] : 0.f;
        }
        if (active) {
            const float* buf = tf + (cl & 1) * 2784;
            const int ci = c & 127;
            const float* wp0 = gw0 + ((size_t)g * 128 + ci) * 27;
            const float* wp1 = gw1 + ((size_t)g * 128 + ci) * 27;
            #pragma unroll
            for (int t = 0; t < 8; ++t) {
                float v[9];
                #pragma unroll
                for (int ki = 0; ki < 3; ++ki)
                    #pragma unroll
                    for (int kj = 0; kj < 3; ++kj)
                        v[ki * 3 + kj] = buf[t * 348 + (hr + ki) * 58 + wc + kj];
                #pragma unroll
                for (int kd = 0; kd < 3; ++kd) {
                    {
                        const int to = t + 1 - kd;
                        if (to >= 0 && to < 8) {
                            float s = 0.f;
                            #pragma unroll
                            for (int k = 0; k < 9; ++k) s = fmaf(wp0[kd * 9 + k], v[k], s);
                            acc[0][to] += s;
                        }
                    }
                    {
                        const int to = t + 2 - 2 * kd;
                        if (to >= 0 && to < 8) {
                            float s = 0.f;
                            #pragma unroll
                            for (int k = 0; k < 9; ++k) s = fmaf(wp1[kd * 9 + k], v[k], s);
                            acc[1][to] += s;
                        }
                    }
                }
            }
        }
        if (cl < 7) {
            const float scn = scale[c + 1], shn = shift[c + 1];
            float* bufn = tf + ((cl + 1) & 1) * 2784;
            #pragma unroll
            for (int k = 0; k < 11; ++k)
                if (vld[k])
                    bufn[soff[k]] = fmaxf(fmaf(xv[k] * av[k], scn, shn), 0.f);
        }
        __syncthreads();
    }

    if (active) {
        const int hw = (h0 + hr) * WW + wc;
        #pragma unroll
        for (int d = 0; d < 2; ++d)
            #pragma unroll
            for (int t = 0; t < 8; ++t)
                atomicAdd(&gate_raw[(((size_t)(d * 4 + b) * 2 + g) * 8 + t) * HW + hw],
                          acc[d][t]);
    }
}

// ---------------- K4b: gate = tanh(raw + bias) ----------------------------
__global__ void k4b_tanh(const float* __restrict__ raw, const float* __restrict__ gb0,
                         const float* __restrict__ gb1, float* __restrict__ gt) {
    int i = blockIdx.x * 256 + threadIdx.x;
    if (i >= 401408) return;
    int d   = i / 200704;
    int rem = i - d * 200704;
    int g   = (rem / 25088) & 1;
    float bias = (d == 0) ? gb0[g] : gb1[g];
    gt[i] = tanhf(raw[i] + bias);
}

// ---------------- K5: fuse + shuffle + alpha-combine ----------------------
__global__ __launch_bounds__(256)
void k5_fuse(const float* __restrict__ x, const float* __restrict__ attn,
             const float* __restrict__ scale, const float* __restrict__ shift,
             const float* __restrict__ gt, const float* __restrict__ alpha,
             float* __restrict__ out) {
    const int blk  = blockIdx.x;
    const int tile = blk % 13;
    const int c    = (blk / 13) & 255;
    const int b    = blk / (13 * 256);
    const int hw   = tile * 256 + threadIdx.x;
    if (hw >= HW) return;
    const int clo  = c & 127;
    const int cs   = (c & 128) | ((clo & 1) << 6) | (clo >> 1);  // inverse shuffle
    const int g    = c >> 7;
    const int head = cs >> 6;
    const float sc = scale[cs], sh = shift[cs];
    float xr[8], G0[8], G1[8];
    #pragma unroll
    for (int t = 0; t < 8; ++t) {
        const int bti = b * 8 + t;
        float xv = x[((size_t)bti * CC + cs) * HW + hw];
        float av = attn[((size_t)bti * 4 + head) * HW + hw];
        xr[t] = fmaxf(fmaf(xv * av, sc, sh), 0.f);
        G0[t] = gt[(((size_t)(0 * 4 + b) * 2 + g) * 8 + t) * HW + hw];
        G1[t] = gt[(((size_t)(1 * 4 + b) * 2 + g) * 8 + t) * HW + hw];
    }
    const float a0 = alpha[0], a1 = alpha[1];
    #pragma unroll
    for (int t = 0; t < 8; ++t) {
        float v0, v1;
        if (g == 0) {
            v0 = xr[t] * (1.f - G0[t]) + (t + 1 < 8 ? G0[t + 1] * xr[t + 1] : 0.f);
            v1 = xr[t] * (1.f - G1[t]) + (t + 2 < 8 ? G1[t + 2] * xr[t + 2] : 0.f);
        } else {
            v0 = xr[t] * (1.f - G0[t]) + (t - 1 >= 0 ? G0[t - 1] * xr[t - 1] : 0.f);
            v1 = xr[t] * (1.f - G1[t]) + (t - 2 >= 0 ? G1[t - 2] * xr[t - 2] : 0.f);
        }
        out[((size_t)(b * 8 + t) * CC + c) * HW + hw] = fmaf(a0, v0, a1 * v1);
    }
}

extern "C" void kernel_launch(void* const* d_in, const int* in_sizes, int n_in,
                              void* d_out, int out_size, void* d_ws, size_t ws_size,
                              hipStream_t stream) {
    const float* x     = (const float*)d_in[0];
    const float* aw    = (const float*)d_in[1];
    const float* ab    = (const float*)d_in[2];
    const float* gamma = (const float*)d_in[3];
    const float* beta  = (const float*)d_in[4];
    const float* gw0   = (const float*)d_in[5];
    const float* gb0   = (const float*)d_in[6];
    const float* gw1   = (const float*)d_in[7];
    const float* gb1   = (const float*)d_in[8];
    const float* alpha = (const float*)d_in[9];
    float* out = (float*)d_out;
    float* ws  = (float*)d_ws;

    // ws layout (floats):
    //   [gate_raw 401408 | attn_raw/gate_t 401408 | bn_sum 256 | bn_sumsq 256 |
    //    attn 401408 | scale 256 | shift 256]
    float* gate_raw = ws;
    float* attn_raw = ws + 401408;
    float* gate_t   = attn_raw;             // alias (timeline-disjoint)
    float* bn_sum   = ws + 802816;
    float* bn_sumsq = ws + 803072;
    float* attn     = ws + 803328;
    float* scale    = ws + 1204736;
    float* shift    = ws + 1204992;

    // zero all atomic-accumulated regions in one memset (contiguous prefix)
    hipMemsetAsync(ws, 0, (size_t)(401408 + 401408 + 512) * sizeof(float), stream);

    k1_attn <<<dim3(1792),  dim3(256), 0, stream>>>(x, aw, attn_raw);
    k1b_act <<<dim3(1568),  dim3(256), 0, stream>>>(attn_raw, ab, attn);
    k2_stats<<<dim3(8192),  dim3(256), 0, stream>>>(x, attn, bn_sum, bn_sumsq);
    k3_final<<<dim3(1),     dim3(256), 0, stream>>>(bn_sum, bn_sumsq, gamma, beta, scale, shift);
    k4_gate <<<dim3(1792),  dim3(256), 0, stream>>>(x, attn, scale, shift, gw0, gw1, gate_raw);
    k4b_tanh<<<dim3(1568),  dim3(256), 0, stream>>>(gate_raw, gb0, gb1, gate_t);
    k5_fuse <<<dim3(13312), dim3(256), 0, stream>>>(x, attn, scale, shift, gate_t, alpha, out);
}

// Round 10
// 185.121 us; speedup vs baseline: 1.8972x; 1.1525x over previous
//
#include <hip/hip_runtime.h>
#include <math.h>

#define HH 56
#define WW 56
#define CC 256
#define TT 8
#define HW 3136

// ---------------- K1: attn conv2d, LDS-staged, double-buffered ------------
__global__ __launch_bounds__(256)
void k1_attn(const float* __restrict__ x, const float* __restrict__ aw,
             float* __restrict__ attn_raw) {
    const int blk = blockIdx.x;
    const int cs  = blk & 3;
    const int ht  = (blk >> 2) % 14;
    const int bt  = blk / 56;
    const int h0  = ht * 4;
    __shared__ float tile[2][6 * 58];       // 2784 B
    float* tf = &tile[0][0];
    const int tid = threadIdx.x;
    const float* xb = x + ((size_t)bt * CC + cs * 64) * HW;

    int  soff[2], goff[2];
    bool vld[2];
    #pragma unroll
    for (int k = 0; k < 2; ++k) {
        int idx = tid + k * 256;
        bool in = idx < 6 * 58;
        int r   = idx / 58;
        int col = idx - r * 58;
        int gh = h0 + r - 1, gw = col - 1;
        bool v = in && (unsigned)gh < HH && (unsigned)gw < WW;
        vld[k]  = v;
        soff[k] = idx;
        goff[k] = gh * WW + gw;
        if (in && !v) { tf[idx] = 0.f; tf[348 + idx] = 0.f; }  // zero halo once
    }

    #pragma unroll
    for (int k = 0; k < 2; ++k)
        if (vld[k]) tf[soff[k]] = xb[goff[k]];
    __syncthreads();

    const int wc = tid % WW;
    const int hr = tid / WW;
    const bool active = tid < 4 * WW;
    float acc[4] = {0.f, 0.f, 0.f, 0.f};

    for (int cl = 0; cl < 64; ++cl) {
        float xv[2];
        if (cl < 63) {
            #pragma unroll
            for (int k = 0; k < 2; ++k)
                xv[k] = vld[k] ? xb[(size_t)(cl + 1) * HW + goff[k]] : 0.f;
        }
        if (active) {
            const float* buf = tf + (cl & 1) * 348;
            float v[9];
            #pragma unroll
            for (int ki = 0; ki < 3; ++ki)
                #pragma unroll
                for (int kj = 0; kj < 3; ++kj)
                    v[ki * 3 + kj] = buf[(hr + ki) * 58 + wc + kj];
            const int c = cs * 64 + cl;
            #pragma unroll
            for (int h = 0; h < 4; ++h) {
                const float* w = aw + ((size_t)h * CC + c) * 9;
                float s = 0.f;
                #pragma unroll
                for (int k = 0; k < 9; ++k) s = fmaf(w[k], v[k], s);
                acc[h] += s;
            }
        }
        if (cl < 63) {
            float* bufn = tf + ((cl + 1) & 1) * 348;
            #pragma unroll
            for (int k = 0; k < 2; ++k)
                if (vld[k]) bufn[soff[k]] = xv[k];
        }
        __syncthreads();
    }

    if (active) {
        const int base = (h0 + hr) * WW + wc;
        #pragma unroll
        for (int h = 0; h < 4; ++h)
            atomicAdd(&attn_raw[((size_t)bt * 4 + h) * HW + base], acc[h]);
    }
}

// ---------------- K1b: attn = sigmoid(relu(raw + bias)) -------------------
__global__ void k1b_act(const float* __restrict__ raw, const float* __restrict__ ab,
                        float* __restrict__ attn) {
    int i = blockIdx.x * 256 + threadIdx.x;
    if (i >= 32 * 4 * HW) return;
    int o = (i / HW) & 3;
    float z = fmaxf(raw[i] + ab[o], 0.f);
    attn[i] = 1.f / (1.f + expf(-z));
}

// ---------------- K2: per-channel BN partial sums of xh = x*attn ----------
__global__ __launch_bounds__(256)
void k2_stats(const float* __restrict__ x, const float* __restrict__ attn,
              float* __restrict__ bn_sum, float* __restrict__ bn_sumsq) {
    const int c  = blockIdx.x & 255;
    const int bt = blockIdx.x >> 8;
    const int head = c >> 6;
    const float4* xp = (const float4*)(x + ((size_t)bt * CC + c) * HW);
    const float4* ap = (const float4*)(attn + ((size_t)bt * 4 + head) * HW);
    float s = 0.f, s2 = 0.f;
    for (int i = threadIdx.x; i < HW / 4; i += 256) {
        float4 xv = xp[i], av = ap[i];
        float v0 = xv.x * av.x, v1 = xv.y * av.y, v2 = xv.z * av.z, v3 = xv.w * av.w;
        s  += v0 + v1 + v2 + v3;
        s2 += v0 * v0 + v1 * v1 + v2 * v2 + v3 * v3;
    }
    #pragma unroll
    for (int off = 32; off > 0; off >>= 1) {
        s  += __shfl_down(s, off);
        s2 += __shfl_down(s2, off);
    }
    __shared__ float red[8];
    const int wave = threadIdx.x >> 6;
    if ((threadIdx.x & 63) == 0) { red[wave * 2] = s; red[wave * 2 + 1] = s2; }
    __syncthreads();
    if (threadIdx.x == 0) {
        atomicAdd(&bn_sum[c],   red[0] + red[2] + red[4] + red[6]);
        atomicAdd(&bn_sumsq[c], red[1] + red[3] + red[5] + red[7]);
    }
}

// ---------------- K3: finalize BN -> per-channel scale/shift --------------
__global__ void k3_final(const float* __restrict__ bn_sum, const float* __restrict__ bn_sumsq,
                         const float* __restrict__ gamma, const float* __restrict__ beta,
                         float* __restrict__ scale, float* __restrict__ shift) {
    int c = threadIdx.x;
    const float invN = 1.f / 100352.f;            // B*T*H*W
    float mean = bn_sum[c] * invN;
    float var  = bn_sumsq[c] * invN - mean * mean;
    float sc   = gamma[c] * rsqrtf(var + 1e-5f);
    scale[c] = sc;
    shift[c] = fmaf(-mean, sc, beta[c]);
}

// ---------------- K4: grouped dilated conv3d, t-vectorized LDS ------------
// LDS layout [pos][t0..t7 pad to 12 dwords]: one tap read = 2x ds_read_b128
// (all 8 t at once) instead of 8x ds_read_b32. 48B position stride keeps
// 16B alignment and spreads banks. Was LDS-read-pipe-bound (576 b32
// reads/thread); now 144 b128 reads/thread. Schedule (prefetch regs ->
// compute -> write other buffer -> 1 barrier/channel) unchanged.
__global__ __launch_bounds__(256)
void k4_gate(const float* __restrict__ x, const float* __restrict__ attn,
             const float* __restrict__ scale, const float* __restrict__ shift,
             const float* __restrict__ gw0, const float* __restrict__ gw1,
             float* __restrict__ gate_raw) {
    const int blk   = blockIdx.x;
    const int chunk = blk & 31;             // 32 chunks x 8 channels
    const int ht    = (blk >> 5) % 14;
    const int b     = blk / (32 * 14);
    const int h0    = ht * 4;
    const int g     = chunk >> 4;           // group: ch 0..127 -> 0, else 1
    const int head  = chunk >> 3;           // 8-ch chunk sits inside one head
    __shared__ float tile[2][348 * 12];     // 33408 B
    const int tid = threadIdx.x;

    // position descriptors: p = tid, tid+256 (348 spatial positions w/ halo)
    int   pgoff[2];
    bool  pvld[2];
    float pav[2][8];
    #pragma unroll
    for (int k = 0; k < 2; ++k) {
        int p = tid + k * 256;
        bool in = p < 348;
        int r   = p / 58;
        int col = p - r * 58;
        int gh = h0 + r - 1, gw = col - 1;
        bool v = in && (unsigned)gh < HH && (unsigned)gw < WW;
        pvld[k]  = v;
        pgoff[k] = gh * WW + gw;
        #pragma unroll
        for (int t = 0; t < 8; ++t)
            pav[k][t] = v ? attn[((size_t)(b * 8 + t) * 4 + head) * HW + pgoff[k]] : 0.f;
        if (in && !v) {                      // zero halo once, both buffers
            float4 z = make_float4(0.f, 0.f, 0.f, 0.f);
            *(float4*)&tile[0][p * 12]     = z;
            *(float4*)&tile[0][p * 12 + 4] = z;
            *(float4*)&tile[1][p * 12]     = z;
            *(float4*)&tile[1][p * 12 + 4] = z;
        }
    }

    // stage channel 0 into buffer 0
    {
        const int c0 = chunk * 8;
        const float sc = scale[c0], sh = shift[c0];
        #pragma unroll
        for (int k = 0; k < 2; ++k)
            if (pvld[k]) {
                float v[8];
                #pragma unroll
                for (int t = 0; t < 8; ++t) {
                    float xv = x[((size_t)((b * 8 + t) * CC + c0)) * HW + pgoff[k]];
                    v[t] = fmaxf(fmaf(xv * pav[k][t], sc, sh), 0.f);
                }
                int p = tid + k * 256;
                *(float4*)&tile[0][p * 12]     = make_float4(v[0], v[1], v[2], v[3]);
                *(float4*)&tile[0][p * 12 + 4] = make_float4(v[4], v[5], v[6], v[7]);
            }
    }
    __syncthreads();

    const int wc = tid % WW;
    const int hr = tid / WW;
    const bool active = tid < 4 * WW;
    float acc[2][8];
    #pragma unroll
    for (int d = 0; d < 2; ++d)
        #pragma unroll
        for (int t = 0; t < 8; ++t) acc[d][t] = 0.f;

    for (int cl = 0; cl < 8; ++cl) {
        const int c = chunk * 8 + cl;
        // prefetch raw x for next channel (latency hidden under compute)
        float xn[2][8];
        if (cl < 7) {
            #pragma unroll
            for (int k = 0; k < 2; ++k)
                if (pvld[k]) {
                    #pragma unroll
                    for (int t = 0; t < 8; ++t)
                        xn[k][t] = x[((size_t)((b * 8 + t) * CC + c + 1)) * HW + pgoff[k]];
                }
        }
        // compute current channel from LDS buffer (cl&1)
        if (active) {
            const float* buf = &tile[cl & 1][0];
            const int ci = c & 127;
            const float* wp0 = gw0 + ((size_t)g * 128 + ci) * 27;
            const float* wp1 = gw1 + ((size_t)g * 128 + ci) * 27;
            #pragma unroll
            for (int ki = 0; ki < 3; ++ki) {
                #pragma unroll
                for (int kj = 0; kj < 3; ++kj) {
                    const int tap = ki * 3 + kj;
                    const int pos = (hr + ki) * 58 + wc + kj;
                    const float4 A = *(const float4*)(buf + pos * 12);
                    const float4 B = *(const float4*)(buf + pos * 12 + 4);
                    const float vv[8] = {A.x, A.y, A.z, A.w, B.x, B.y, B.z, B.w};
                    #pragma unroll
                    for (int kd = 0; kd < 3; ++kd) {
                        const float w0 = wp0[kd * 9 + tap];
                        const float w1 = wp1[kd * 9 + tap];
                        #pragma unroll
                        for (int t = 0; t < 8; ++t) {
                            const int to1 = t + 1 - kd;
                            if (to1 >= 0 && to1 < 8)
                                acc[0][to1] = fmaf(w0, vv[t], acc[0][to1]);
                            const int to2 = t + 2 - 2 * kd;
                            if (to2 >= 0 && to2 < 8)
                                acc[1][to2] = fmaf(w1, vv[t], acc[1][to2]);
                        }
                    }
                }
            }
        }
        // write prefetched channel (transformed to xr) into other buffer
        if (cl < 7) {
            const float scn = scale[c + 1], shn = shift[c + 1];
            float* bufn = &tile[(cl + 1) & 1][0];
            #pragma unroll
            for (int k = 0; k < 2; ++k)
                if (pvld[k]) {
                    float v[8];
                    #pragma unroll
                    for (int t = 0; t < 8; ++t)
                        v[t] = fmaxf(fmaf(xn[k][t] * pav[k][t], scn, shn), 0.f);
                    int p = tid + k * 256;
                    *(float4*)&bufn[p * 12]     = make_float4(v[0], v[1], v[2], v[3]);
                    *(float4*)&bufn[p * 12 + 4] = make_float4(v[4], v[5], v[6], v[7]);
                }
        }
        __syncthreads();
    }

    if (active) {
        const int hw = (h0 + hr) * WW + wc;
        #pragma unroll
        for (int d = 0; d < 2; ++d)
            #pragma unroll
            for (int t = 0; t < 8; ++t)
                atomicAdd(&gate_raw[(((size_t)(d * 4 + b) * 2 + g) * 8 + t) * HW + hw],
                          acc[d][t]);
    }
}

// ---------------- K4b: gate = tanh(raw + bias) ----------------------------
__global__ void k4b_tanh(const float* __restrict__ raw, const float* __restrict__ gb0,
                         const float* __restrict__ gb1, float* __restrict__ gt) {
    int i = blockIdx.x * 256 + threadIdx.x;
    if (i >= 401408) return;
    int d   = i / 200704;
    int rem = i - d * 200704;
    int g   = (rem / 25088) & 1;
    float bias = (d == 0) ? gb0[g] : gb1[g];
    gt[i] = tanhf(raw[i] + bias);
}

// ---------------- K5: fuse + shuffle + alpha-combine ----------------------
__global__ __launch_bounds__(256)
void k5_fuse(const float* __restrict__ x, const float* __restrict__ attn,
             const float* __restrict__ scale, const float* __restrict__ shift,
             const float* __restrict__ gt, const float* __restrict__ alpha,
             float* __restrict__ out) {
    const int blk  = blockIdx.x;
    const int tile = blk % 13;
    const int c    = (blk / 13) & 255;
    const int b    = blk / (13 * 256);
    const int hw   = tile * 256 + threadIdx.x;
    if (hw >= HW) return;
    const int clo  = c & 127;
    const int cs   = (c & 128) | ((clo & 1) << 6) | (clo >> 1);  // inverse shuffle
    const int g    = c >> 7;
    const int head = cs >> 6;
    const float sc = scale[cs], sh = shift[cs];
    float xr[8], G0[8], G1[8];
    #pragma unroll
    for (int t = 0; t < 8; ++t) {
        const int bti = b * 8 + t;
        float xv = x[((size_t)bti * CC + cs) * HW + hw];
        float av = attn[((size_t)bti * 4 + head) * HW + hw];
        xr[t] = fmaxf(fmaf(xv * av, sc, sh), 0.f);
        G0[t] = gt[(((size_t)(0 * 4 + b) * 2 + g) * 8 + t) * HW + hw];
        G1[t] = gt[(((size_t)(1 * 4 + b) * 2 + g) * 8 + t) * HW + hw];
    }
    const float a0 = alpha[0], a1 = alpha[1];
    #pragma unroll
    for (int t = 0; t < 8; ++t) {
        float v0, v1;
        if (g == 0) {
            v0 = xr[t] * (1.f - G0[t]) + (t + 1 < 8 ? G0[t + 1] * xr[t + 1] : 0.f);
            v1 = xr[t] * (1.f - G1[t]) + (t + 2 < 8 ? G1[t + 2] * xr[t + 2] : 0.f);
        } else {
            v0 = xr[t] * (1.f - G0[t]) + (t - 1 >= 0 ? G0[t - 1] * xr[t - 1] : 0.f);
            v1 = xr[t] * (1.f - G1[t]) + (t - 2 >= 0 ? G1[t - 2] * xr[t - 2] : 0.f);
        }
        out[((size_t)(b * 8 + t) * CC + c) * HW + hw] = fmaf(a0, v0, a1 * v1);
    }
}

extern "C" void kernel_launch(void* const* d_in, const int* in_sizes, int n_in,
                              void* d_out, int out_size, void* d_ws, size_t ws_size,
                              hipStream_t stream) {
    const float* x     = (const float*)d_in[0];
    const float* aw    = (const float*)d_in[1];
    const float* ab    = (const float*)d_in[2];
    const float* gamma = (const float*)d_in[3];
    const float* beta  = (const float*)d_in[4];
    const float* gw0   = (const float*)d_in[5];
    const float* gb0   = (const float*)d_in[6];
    const float* gw1   = (const float*)d_in[7];
    const float* gb1   = (const float*)d_in[8];
    const float* alpha = (const float*)d_in[9];
    float* out = (float*)d_out;
    float* ws  = (float*)d_ws;

    // ws layout (floats):
    //   [gate_raw 401408 | attn_raw/gate_t 401408 | bn_sum 256 | bn_sumsq 256 |
    //    attn 401408 | scale 256 | shift 256]
    float* gate_raw = ws;
    float* attn_raw = ws + 401408;
    float* gate_t   = attn_raw;             // alias (timeline-disjoint)
    float* bn_sum   = ws + 802816;
    float* bn_sumsq = ws + 803072;
    float* attn     = ws + 803328;
    float* scale    = ws + 1204736;
    float* shift    = ws + 1204992;

    // zero all atomic-accumulated regions in one memset (contiguous prefix)
    hipMemsetAsync(ws, 0, (size_t)(401408 + 401408 + 512) * sizeof(float), stream);

    k1_attn <<<dim3(1792),  dim3(256), 0, stream>>>(x, aw, attn_raw);
    k1b_act <<<dim3(1568),  dim3(256), 0, stream>>>(attn_raw, ab, attn);
    k2_stats<<<dim3(8192),  dim3(256), 0, stream>>>(x, attn, bn_sum, bn_sumsq);
    k3_final<<<dim3(1),     dim3(256), 0, stream>>>(bn_sum, bn_sumsq, gamma, beta, scale, shift);
    k4_gate <<<dim3(1792),  dim3(256), 0, stream>>>(x, attn, scale, shift, gw0, gw1, gate_raw);
    k4b_tanh<<<dim3(1568),  dim3(256), 0, stream>>>(gate_raw, gb0, gb1, gate_t);
    k5_fuse <<<dim3(13312), dim3(256), 0, stream>>>(x, attn, scale, shift, gate_t, alpha, out);
}

// Round 11
// 174.614 us; speedup vs baseline: 2.0114x; 1.0602x over previous
//
#include <hip/hip_runtime.h>
#include <math.h>

#define HH 56
#define WW 56
#define CC 256
#define TT 8
#define HW 3136

// ---------------- K1: attn conv2d, channel-vectorized LDS -----------------
// Same fix that took k4 94->~45us: LDS layout [pos][c0..c3] so one tap read
// = 1x ds_read_b128 (4 channels at once). Per 4-ch group: 9 b128 reads +
// 2 b128 writes feed 144 FMAs; 16 barriers/block (was 64). Prefetch next
// group to regs before compute, write after, one barrier per group.
// grid = bt(32) x band(14) x csplit(4 of 64ch) = 1792 blocks.
__global__ __launch_bounds__(256)
void k1_attn(const float* __restrict__ x, const float* __restrict__ aw,
             float* __restrict__ attn_raw) {
    const int blk = blockIdx.x;
    const int cs  = blk & 3;
    const int ht  = (blk >> 2) % 14;
    const int bt  = blk / 56;
    const int h0  = ht * 4;
    __shared__ float tile[2][348 * 4];      // 11136 B
    const int tid = threadIdx.x;
    const float* xb = x + ((size_t)bt * CC + cs * 64) * HW;

    // position descriptors (channel-independent): p = tid, tid+256
    int  pgoff[2];
    bool pvld[2];
    #pragma unroll
    for (int k = 0; k < 2; ++k) {
        int p = tid + k * 256;
        bool in = p < 348;
        int r   = p / 58;
        int col = p - r * 58;
        int gh = h0 + r - 1, gw = col - 1;
        bool v = in && (unsigned)gh < HH && (unsigned)gw < WW;
        pvld[k]  = v;
        pgoff[k] = gh * WW + gw;
        if (in && !v) {                      // zero halo once, both buffers
            float4 z = make_float4(0.f, 0.f, 0.f, 0.f);
            *(float4*)&tile[0][p * 4] = z;
            *(float4*)&tile[1][p * 4] = z;
        }
    }

    // stage channel group 0 into buffer 0
    #pragma unroll
    for (int k = 0; k < 2; ++k)
        if (pvld[k]) {
            float v0 = xb[(size_t)0 * HW + pgoff[k]];
            float v1 = xb[(size_t)1 * HW + pgoff[k]];
            float v2 = xb[(size_t)2 * HW + pgoff[k]];
            float v3 = xb[(size_t)3 * HW + pgoff[k]];
            *(float4*)&tile[0][(tid + k * 256) * 4] = make_float4(v0, v1, v2, v3);
        }
    __syncthreads();

    const int wc = tid % WW;
    const int hr = tid / WW;
    const bool active = tid < 4 * WW;
    float acc[4] = {0.f, 0.f, 0.f, 0.f};

    for (int it = 0; it < 16; ++it) {
        const int c0 = cs * 64 + it * 4;
        // prefetch next 4-channel group into regs
        float xn[2][4];
        if (it < 15) {
            #pragma unroll
            for (int k = 0; k < 2; ++k)
                if (pvld[k]) {
                    #pragma unroll
                    for (int j = 0; j < 4; ++j)
                        xn[k][j] = xb[(size_t)(it * 4 + 4 + j) * HW + pgoff[k]];
                }
        }
        // compute current group from LDS buffer (it&1)
        if (active) {
            const float* buf = &tile[it & 1][0];
            const float* w0 = aw + ((size_t)0 * CC + c0) * 9;  // head 0, ch c0..c0+3
            const float* w1 = aw + ((size_t)1 * CC + c0) * 9;
            const float* w2 = aw + ((size_t)2 * CC + c0) * 9;
            const float* w3 = aw + ((size_t)3 * CC + c0) * 9;
            #pragma unroll
            for (int ki = 0; ki < 3; ++ki) {
                #pragma unroll
                for (int kj = 0; kj < 3; ++kj) {
                    const int tap = ki * 3 + kj;
                    const int pos = (hr + ki) * 58 + wc + kj;
                    const float4 v = *(const float4*)(buf + pos * 4);
                    acc[0] = fmaf(w0[tap],      v.x, acc[0]);
                    acc[0] = fmaf(w0[9  + tap], v.y, acc[0]);
                    acc[0] = fmaf(w0[18 + tap], v.z, acc[0]);
                    acc[0] = fmaf(w0[27 + tap], v.w, acc[0]);
                    acc[1] = fmaf(w1[tap],      v.x, acc[1]);
                    acc[1] = fmaf(w1[9  + tap], v.y, acc[1]);
                    acc[1] = fmaf(w1[18 + tap], v.z, acc[1]);
                    acc[1] = fmaf(w1[27 + tap], v.w, acc[1]);
                    acc[2] = fmaf(w2[tap],      v.x, acc[2]);
                    acc[2] = fmaf(w2[9  + tap], v.y, acc[2]);
                    acc[2] = fmaf(w2[18 + tap], v.z, acc[2]);
                    acc[2] = fmaf(w2[27 + tap], v.w, acc[2]);
                    acc[3] = fmaf(w3[tap],      v.x, acc[3]);
                    acc[3] = fmaf(w3[9  + tap], v.y, acc[3]);
                    acc[3] = fmaf(w3[18 + tap], v.z, acc[3]);
                    acc[3] = fmaf(w3[27 + tap], v.w, acc[3]);
                }
            }
        }
        // write prefetched group into other buffer
        if (it < 15) {
            float* bufn = &tile[(it + 1) & 1][0];
            #pragma unroll
            for (int k = 0; k < 2; ++k)
                if (pvld[k])
                    *(float4*)&bufn[(tid + k * 256) * 4] =
                        make_float4(xn[k][0], xn[k][1], xn[k][2], xn[k][3]);
        }
        __syncthreads();
    }

    if (active) {
        const int base = (h0 + hr) * WW + wc;
        #pragma unroll
        for (int h = 0; h < 4; ++h)
            atomicAdd(&attn_raw[((size_t)bt * 4 + h) * HW + base], acc[h]);
    }
}

// ---------------- K1b: attn = sigmoid(relu(raw + bias)) -------------------
__global__ void k1b_act(const float* __restrict__ raw, const float* __restrict__ ab,
                        float* __restrict__ attn) {
    int i = blockIdx.x * 256 + threadIdx.x;
    if (i >= 32 * 4 * HW) return;
    int o = (i / HW) & 3;
    float z = fmaxf(raw[i] + ab[o], 0.f);
    attn[i] = 1.f / (1.f + expf(-z));
}

// ---------------- K2: per-channel BN partial sums of xh = x*attn ----------
__global__ __launch_bounds__(256)
void k2_stats(const float* __restrict__ x, const float* __restrict__ attn,
              float* __restrict__ bn_sum, float* __restrict__ bn_sumsq) {
    const int c  = blockIdx.x & 255;
    const int bt = blockIdx.x >> 8;
    const int head = c >> 6;
    const float4* xp = (const float4*)(x + ((size_t)bt * CC + c) * HW);
    const float4* ap = (const float4*)(attn + ((size_t)bt * 4 + head) * HW);
    float s = 0.f, s2 = 0.f;
    for (int i = threadIdx.x; i < HW / 4; i += 256) {
        float4 xv = xp[i], av = ap[i];
        float v0 = xv.x * av.x, v1 = xv.y * av.y, v2 = xv.z * av.z, v3 = xv.w * av.w;
        s  += v0 + v1 + v2 + v3;
        s2 += v0 * v0 + v1 * v1 + v2 * v2 + v3 * v3;
    }
    #pragma unroll
    for (int off = 32; off > 0; off >>= 1) {
        s  += __shfl_down(s, off);
        s2 += __shfl_down(s2, off);
    }
    __shared__ float red[8];
    const int wave = threadIdx.x >> 6;
    if ((threadIdx.x & 63) == 0) { red[wave * 2] = s; red[wave * 2 + 1] = s2; }
    __syncthreads();
    if (threadIdx.x == 0) {
        atomicAdd(&bn_sum[c],   red[0] + red[2] + red[4] + red[6]);
        atomicAdd(&bn_sumsq[c], red[1] + red[3] + red[5] + red[7]);
    }
}

// ---------------- K3: finalize BN -> per-channel scale/shift --------------
__global__ void k3_final(const float* __restrict__ bn_sum, const float* __restrict__ bn_sumsq,
                         const float* __restrict__ gamma, const float* __restrict__ beta,
                         float* __restrict__ scale, float* __restrict__ shift) {
    int c = threadIdx.x;
    const float invN = 1.f / 100352.f;            // B*T*H*W
    float mean = bn_sum[c] * invN;
    float var  = bn_sumsq[c] * invN - mean * mean;
    float sc   = gamma[c] * rsqrtf(var + 1e-5f);
    scale[c] = sc;
    shift[c] = fmaf(-mean, sc, beta[c]);
}

// ---------------- K4: grouped dilated conv3d, t-vectorized LDS ------------
__global__ __launch_bounds__(256)
void k4_gate(const float* __restrict__ x, const float* __restrict__ attn,
             const float* __restrict__ scale, const float* __restrict__ shift,
             const float* __restrict__ gw0, const float* __restrict__ gw1,
             float* __restrict__ gate_raw) {
    const int blk   = blockIdx.x;
    const int chunk = blk & 31;             // 32 chunks x 8 channels
    const int ht    = (blk >> 5) % 14;
    const int b     = blk / (32 * 14);
    const int h0    = ht * 4;
    const int g     = chunk >> 4;           // group: ch 0..127 -> 0, else 1
    const int head  = chunk >> 3;           // 8-ch chunk sits inside one head
    __shared__ float tile[2][348 * 12];     // 33408 B
    const int tid = threadIdx.x;

    int   pgoff[2];
    bool  pvld[2];
    float pav[2][8];
    #pragma unroll
    for (int k = 0; k < 2; ++k) {
        int p = tid + k * 256;
        bool in = p < 348;
        int r   = p / 58;
        int col = p - r * 58;
        int gh = h0 + r - 1, gw = col - 1;
        bool v = in && (unsigned)gh < HH && (unsigned)gw < WW;
        pvld[k]  = v;
        pgoff[k] = gh * WW + gw;
        #pragma unroll
        for (int t = 0; t < 8; ++t)
            pav[k][t] = v ? attn[((size_t)(b * 8 + t) * 4 + head) * HW + pgoff[k]] : 0.f;
        if (in && !v) {
            float4 z = make_float4(0.f, 0.f, 0.f, 0.f);
            *(float4*)&tile[0][p * 12]     = z;
            *(float4*)&tile[0][p * 12 + 4] = z;
            *(float4*)&tile[1][p * 12]     = z;
            *(float4*)&tile[1][p * 12 + 4] = z;
        }
    }

    {
        const int c0 = chunk * 8;
        const float sc = scale[c0], sh = shift[c0];
        #pragma unroll
        for (int k = 0; k < 2; ++k)
            if (pvld[k]) {
                float v[8];
                #pragma unroll
                for (int t = 0; t < 8; ++t) {
                    float xv = x[((size_t)((b * 8 + t) * CC + c0)) * HW + pgoff[k]];
                    v[t] = fmaxf(fmaf(xv * pav[k][t], sc, sh), 0.f);
                }
                int p = tid + k * 256;
                *(float4*)&tile[0][p * 12]     = make_float4(v[0], v[1], v[2], v[3]);
                *(float4*)&tile[0][p * 12 + 4] = make_float4(v[4], v[5], v[6], v[7]);
            }
    }
    __syncthreads();

    const int wc = tid % WW;
    const int hr = tid / WW;
    const bool active = tid < 4 * WW;
    float acc[2][8];
    #pragma unroll
    for (int d = 0; d < 2; ++d)
        #pragma unroll
        for (int t = 0; t < 8; ++t) acc[d][t] = 0.f;

    for (int cl = 0; cl < 8; ++cl) {
        const int c = chunk * 8 + cl;
        float xn[2][8];
        if (cl < 7) {
            #pragma unroll
            for (int k = 0; k < 2; ++k)
                if (pvld[k]) {
                    #pragma unroll
                    for (int t = 0; t < 8; ++t)
                        xn[k][t] = x[((size_t)((b * 8 + t) * CC + c + 1)) * HW + pgoff[k]];
                }
        }
        if (active) {
            const float* buf = &tile[cl & 1][0];
            const int ci = c & 127;
            const float* wp0 = gw0 + ((size_t)g * 128 + ci) * 27;
            const float* wp1 = gw1 + ((size_t)g * 128 + ci) * 27;
            #pragma unroll
            for (int ki = 0; ki < 3; ++ki) {
                #pragma unroll
                for (int kj = 0; kj < 3; ++kj) {
                    const int tap = ki * 3 + kj;
                    const int pos = (hr + ki) * 58 + wc + kj;
                    const float4 A = *(const float4*)(buf + pos * 12);
                    const float4 B = *(const float4*)(buf + pos * 12 + 4);
                    const float vv[8] = {A.x, A.y, A.z, A.w, B.x, B.y, B.z, B.w};
                    #pragma unroll
                    for (int kd = 0; kd < 3; ++kd) {
                        const float w0 = wp0[kd * 9 + tap];
                        const float w1 = wp1[kd * 9 + tap];
                        #pragma unroll
                        for (int t = 0; t < 8; ++t) {
                            const int to1 = t + 1 - kd;
                            if (to1 >= 0 && to1 < 8)
                                acc[0][to1] = fmaf(w0, vv[t], acc[0][to1]);
                            const int to2 = t + 2 - 2 * kd;
                            if (to2 >= 0 && to2 < 8)
                                acc[1][to2] = fmaf(w1, vv[t], acc[1][to2]);
                        }
                    }
                }
            }
        }
        if (cl < 7) {
            const float scn = scale[c + 1], shn = shift[c + 1];
            float* bufn = &tile[(cl + 1) & 1][0];
            #pragma unroll
            for (int k = 0; k < 2; ++k)
                if (pvld[k]) {
                    float v[8];
                    #pragma unroll
                    for (int t = 0; t < 8; ++t)
                        v[t] = fmaxf(fmaf(xn[k][t] * pav[k][t], scn, shn), 0.f);
                    int p = tid + k * 256;
                    *(float4*)&bufn[p * 12]     = make_float4(v[0], v[1], v[2], v[3]);
                    *(float4*)&bufn[p * 12 + 4] = make_float4(v[4], v[5], v[6], v[7]);
                }
        }
        __syncthreads();
    }

    if (active) {
        const int hw = (h0 + hr) * WW + wc;
        #pragma unroll
        for (int d = 0; d < 2; ++d)
            #pragma unroll
            for (int t = 0; t < 8; ++t)
                atomicAdd(&gate_raw[(((size_t)(d * 4 + b) * 2 + g) * 8 + t) * HW + hw],
                          acc[d][t]);
    }
}

// ---------------- K4b: gate = tanh(raw + bias) ----------------------------
__global__ void k4b_tanh(const float* __restrict__ raw, const float* __restrict__ gb0,
                         const float* __restrict__ gb1, float* __restrict__ gt) {
    int i = blockIdx.x * 256 + threadIdx.x;
    if (i >= 401408) return;
    int d   = i / 200704;
    int rem = i - d * 200704;
    int g   = (rem / 25088) & 1;
    float bias = (d == 0) ? gb0[g] : gb1[g];
    gt[i] = tanhf(raw[i] + bias);
}

// ---------------- K5: fuse + shuffle + alpha-combine ----------------------
__global__ __launch_bounds__(256)
void k5_fuse(const float* __restrict__ x, const float* __restrict__ attn,
             const float* __restrict__ scale, const float* __restrict__ shift,
             const float* __restrict__ gt, const float* __restrict__ alpha,
             float* __restrict__ out) {
    const int blk  = blockIdx.x;
    const int tile = blk % 13;
    const int c    = (blk / 13) & 255;
    const int b    = blk / (13 * 256);
    const int hw   = tile * 256 + threadIdx.x;
    if (hw >= HW) return;
    const int clo  = c & 127;
    const int cs   = (c & 128) | ((clo & 1) << 6) | (clo >> 1);  // inverse shuffle
    const int g    = c >> 7;
    const int head = cs >> 6;
    const float sc = scale[cs], sh = shift[cs];
    float xr[8], G0[8], G1[8];
    #pragma unroll
    for (int t = 0; t < 8; ++t) {
        const int bti = b * 8 + t;
        float xv = x[((size_t)bti * CC + cs) * HW + hw];
        float av = attn[((size_t)bti * 4 + head) * HW + hw];
        xr[t] = fmaxf(fmaf(xv * av, sc, sh), 0.f);
        G0[t] = gt[(((size_t)(0 * 4 + b) * 2 + g) * 8 + t) * HW + hw];
        G1[t] = gt[(((size_t)(1 * 4 + b) * 2 + g) * 8 + t) * HW + hw];
    }
    const float a0 = alpha[0], a1 = alpha[1];
    #pragma unroll
    for (int t = 0; t < 8; ++t) {
        float v0, v1;
        if (g == 0) {
            v0 = xr[t] * (1.f - G0[t]) + (t + 1 < 8 ? G0[t + 1] * xr[t + 1] : 0.f);
            v1 = xr[t] * (1.f - G1[t]) + (t + 2 < 8 ? G1[t + 2] * xr[t + 2] : 0.f);
        } else {
            v0 = xr[t] * (1.f - G0[t]) + (t - 1 >= 0 ? G0[t - 1] * xr[t - 1] : 0.f);
            v1 = xr[t] * (1.f - G1[t]) + (t - 2 >= 0 ? G1[t - 2] * xr[t - 2] : 0.f);
        }
        out[((size_t)(b * 8 + t) * CC + c) * HW + hw] = fmaf(a0, v0, a1 * v1);
    }
}

extern "C" void kernel_launch(void* const* d_in, const int* in_sizes, int n_in,
                              void* d_out, int out_size, void* d_ws, size_t ws_size,
                              hipStream_t stream) {
    const float* x     = (const float*)d_in[0];
    const float* aw    = (const float*)d_in[1];
    const float* ab    = (const float*)d_in[2];
    const float* gamma = (const float*)d_in[3];
    const float* beta  = (const float*)d_in[4];
    const float* gw0   = (const float*)d_in[5];
    const float* gb0   = (const float*)d_in[6];
    const float* gw1   = (const float*)d_in[7];
    const float* gb1   = (const float*)d_in[8];
    const float* alpha = (const float*)d_in[9];
    float* out = (float*)d_out;
    float* ws  = (float*)d_ws;

    // ws layout (floats):
    //   [gate_raw 401408 | attn_raw/gate_t 401408 | bn_sum 256 | bn_sumsq 256 |
    //    attn 401408 | scale 256 | shift 256]
    float* gate_raw = ws;
    float* attn_raw = ws + 401408;
    float* gate_t   = attn_raw;             // alias (timeline-disjoint)
    float* bn_sum   = ws + 802816;
    float* bn_sumsq = ws + 803072;
    float* attn     = ws + 803328;
    float* scale    = ws + 1204736;
    float* shift    = ws + 1204992;

    // zero all atomic-accumulated regions in one memset (contiguous prefix)
    hipMemsetAsync(ws, 0, (size_t)(401408 + 401408 + 512) * sizeof(float), stream);

    k1_attn <<<dim3(1792),  dim3(256), 0, stream>>>(x, aw, attn_raw);
    k1b_act <<<dim3(1568),  dim3(256), 0, stream>>>(attn_raw, ab, attn);
    k2_stats<<<dim3(8192),  dim3(256), 0, stream>>>(x, attn, bn_sum, bn_sumsq);
    k3_final<<<dim3(1),     dim3(256), 0, stream>>>(bn_sum, bn_sumsq, gamma, beta, scale, shift);
    k4_gate <<<dim3(1792),  dim3(256), 0, stream>>>(x, attn, scale, shift, gw0, gw1, gate_raw);
    k4b_tanh<<<dim3(1568),  dim3(256), 0, stream>>>(gate_raw, gb0, gb1, gate_t);
    k5_fuse <<<dim3(13312), dim3(256), 0, stream>>>(x, attn, scale, shift, gate_t, alpha, out);
}